// Round 3
// baseline (1598.404 us; speedup 1.0000x reference)
//
#include <hip/hip_runtime.h>
#include <hip/hip_bf16.h>

#define N_NODES 10000
#define N_EDGES 30000
#define F_NODE  32
#define F_EDGE  8
#define EMB     64
#define HID     16
#define NGRAPH  64

#define M_PAD   10016             // 626 * 16 (GEMM row padding)
#define NCOL    1088              // 1024 U columns + 64 XB columns
#define GRID    512               // co-resident: launch_bounds(256,4) => 4 blk/CU * 256 CU = 1024 >= 512

typedef __attribute__((ext_vector_type(8))) short short8;   // 8 bf16 (MFMA A/B frag)
typedef __attribute__((ext_vector_type(4))) float f32x4;    // MFMA C/D frag

__device__ __forceinline__ unsigned short f2b(float f) {
    __hip_bfloat16 h = __float2bfloat16(f);
    return __builtin_bit_cast(unsigned short, h);
}

// Grid barrier: monotonic counter, device-scope. Requires all blocks co-resident.
__device__ __forceinline__ void gsync(unsigned int* bar, unsigned int target) {
    __threadfence();                                   // publish this thread's writes (agent scope)
    __syncthreads();
    if (threadIdx.x == 0) {
        __hip_atomic_fetch_add(bar, 1u, __ATOMIC_RELEASE, __HIP_MEMORY_SCOPE_AGENT);
        while (__hip_atomic_load(bar, __ATOMIC_ACQUIRE, __HIP_MEMORY_SCOPE_AGENT) < target)
            __builtin_amdgcn_s_sleep(1);
        __threadfence();                               // acquire side: invalidate caches
    }
    __syncthreads();
}

// ---------------------------------------------------------------------------
// Stage: prep. Edge-MLP hiddens (both MLPs), x_p->bf16 (pad zeroed), permuted
// bf16 weights W2p[j=o*16+h][k] (+ b2 appended as cols 1024..1087), XbfB pad
// zero, AGG zero (conv0), POOL zero.
// ---------------------------------------------------------------------------
__device__ void d_prep(const float* __restrict__ ea,
                       const float* __restrict__ w1a, const float* __restrict__ b1a,
                       const float* __restrict__ w1b, const float* __restrict__ b1b,
                       float* __restrict__ A0, float* __restrict__ A1,
                       const float* __restrict__ x_p, unsigned short* __restrict__ Xbf0,
                       const float* __restrict__ w20, const float* __restrict__ b20,
                       unsigned short* __restrict__ W2p0,
                       const float* __restrict__ w21, const float* __restrict__ b21,
                       unsigned short* __restrict__ W2p1,
                       unsigned short* __restrict__ XbfB,
                       float* __restrict__ AGG, float* __restrict__ POOLf) {
    const int gtid = blockIdx.x * 256 + threadIdx.x;
    const int nthr = GRID * 256;
    for (int e = gtid; e < N_EDGES; e += nthr) {       // edge MLP hidden layers
        float f[F_EDGE];
#pragma unroll
        for (int i = 0; i < F_EDGE; i++) f[i] = ea[e * F_EDGE + i];
#pragma unroll
        for (int h = 0; h < HID; h++) {
            float s0 = b1a[h], s1 = b1b[h];
#pragma unroll
            for (int i = 0; i < F_EDGE; i++) {
                s0 += f[i] * w1a[i * HID + h];
                s1 += f[i] * w1b[i * HID + h];
            }
            A0[e * HID + h] = fmaxf(s0, 0.f);
            A1[e * HID + h] = fmaxf(s1, 0.f);
        }
    }
    for (int i = gtid; i < M_PAD * F_NODE; i += nthr)  // x_p -> bf16, pad rows zero
        Xbf0[i] = (i < N_NODES * F_NODE) ? f2b(x_p[i]) : (unsigned short)0;
    for (int i = gtid; i < NCOL * F_NODE; i += nthr) { // W2p0 (K=32)
        int j = i >> 5, k = i & 31;
        float v = (j < 1024) ? w20[(j & 15) * (F_NODE * EMB) + k * EMB + (j >> 4)]
                             : b20[k * EMB + (j - 1024)];
        W2p0[i] = f2b(v);
    }
    for (int i = gtid; i < NCOL * EMB; i += nthr) {    // W2p1 (K=64)
        int j = i >> 6, k = i & 63;
        float v = (j < 1024) ? w21[(j & 15) * (EMB * EMB) + k * EMB + (j >> 4)]
                             : b21[k * EMB + (j - 1024)];
        W2p1[i] = f2b(v);
    }
    for (int i = gtid; i < (M_PAD - N_NODES) * EMB; i += nthr)
        XbfB[N_NODES * EMB + i] = 0;                   // XbfB pad rows
    for (int i = gtid; i < N_NODES * EMB; i += nthr) AGG[i] = 0.f;
    for (int i = gtid; i < NGRAPH * EMB; i += nthr) POOLf[i] = 0.f;
}

// ---------------------------------------------------------------------------
// Stage: MFMA precompute. C[M_PAD x 1088] = Xbf @ W2p^T, K = 32 or 64.
//   cols < 1024 -> U[n][o*16+h] bf16 ; cols >= 1024 -> XB[n][o] fp32
// 16 rows per group, 4 waves x 17 col-tiles; grid-stride over 626 groups.
// ---------------------------------------------------------------------------
template <int K>
__device__ void d_pre(const unsigned short* __restrict__ Xbf,
                      const unsigned short* __restrict__ W2p,
                      unsigned short* __restrict__ U, float* __restrict__ XB) {
    const int t = threadIdx.x;
    const int w = t >> 6, l = t & 63;
    const int lrow = l & 15;
    const int lk = (l >> 4) * 8;
    for (int g = blockIdx.x; g < M_PAD / 16; g += GRID) {
        int n0 = g * 16;
        short8 a[K / 32];
#pragma unroll
        for (int kk = 0; kk < K / 32; kk++)
            a[kk] = *reinterpret_cast<const short8*>(
                Xbf + (size_t)(n0 + lrow) * K + kk * 32 + lk);
        for (int ct = 0; ct < 17; ct++) {
            int c0 = (w * 17 + ct) * 16;
            short8 bf[K / 32];
#pragma unroll
            for (int kk = 0; kk < K / 32; kk++)
                bf[kk] = *reinterpret_cast<const short8*>(
                    W2p + (size_t)(c0 + lrow) * K + kk * 32 + lk);
            f32x4 acc = {0.f, 0.f, 0.f, 0.f};
#pragma unroll
            for (int kk = 0; kk < K / 32; kk++)
                acc = __builtin_amdgcn_mfma_f32_16x16x32_bf16(a[kk], bf[kk], acc, 0, 0, 0);
            int r0 = n0 + (l >> 4) * 4;     // D: row=(l>>4)*4+r, col=l&15
            int col = c0 + lrow;
            if (c0 < 1024) {
#pragma unroll
                for (int r = 0; r < 4; r++)
                    U[(size_t)(r0 + r) * 1024 + col] = f2b(acc[r]);
            } else {
#pragma unroll
                for (int r = 0; r < 4; r++)
                    XB[(size_t)(r0 + r) * EMB + (col - 1024)] = acc[r];
            }
        }
    }
}

// ---------------------------------------------------------------------------
// Stage: gather. One wave per edge (grid-stride):
//   msg[e,o] = XB[s,o] + sum_h A[e,h]*U[s][o*16+h];  atomicAdd into AGG[d,o].
// ---------------------------------------------------------------------------
__device__ void d_gather(const float* __restrict__ A, const unsigned short* __restrict__ U,
                         const float* __restrict__ XB,
                         const int* __restrict__ src, const int* __restrict__ dst,
                         float* __restrict__ AGG) {
    const int w = threadIdx.x >> 6, o = threadIdx.x & 63;
    const int nw = GRID * 4;
    for (int e0 = blockIdx.x * 4 + w; e0 < N_EDGES; e0 += nw) {
        int e = __builtin_amdgcn_readfirstlane(e0);
        int s = src[e], d = dst[e];
        const uint4* up = reinterpret_cast<const uint4*>(U + (size_t)s * 1024 + o * 16);
        uint4 u0 = up[0];
        uint4 u1 = up[1];
        const float* Ae = A + e * HID;          // wave-uniform -> scalar loads
        float a[HID];
#pragma unroll
        for (int h = 0; h < HID; h++) a[h] = Ae[h];
        float m = XB[s * EMB + o];
#define ACC2(wrd, h)                                                              \
        m = fmaf(__builtin_bit_cast(float, (unsigned)(wrd) << 16), a[h], m);      \
        m = fmaf(__builtin_bit_cast(float, (unsigned)(wrd) & 0xffff0000u), a[h + 1], m);
        ACC2(u0.x, 0) ACC2(u0.y, 2) ACC2(u0.z, 4) ACC2(u0.w, 6)
        ACC2(u1.x, 8) ACC2(u1.y, 10) ACC2(u1.z, 12) ACC2(u1.w, 14)
#undef ACC2
        atomicAdd(&AGG[(size_t)d * EMB + o], m);
    }
}

// ---------------------------------------------------------------------------
// Stage: node update. One wave per node (grid-stride). ZAGG re-zeros AGG for
// the next conv (each element read by exactly one thread). In-place X safe.
// ---------------------------------------------------------------------------
template <int IN, bool POOLING, bool WBF, bool ZAGG>
__device__ void d_update(const float* __restrict__ xin, float* __restrict__ AGG,
                         const float* __restrict__ root, const float* __restrict__ bias,
                         const int* __restrict__ batch,
                         float* __restrict__ Xout, unsigned short* __restrict__ Xbf,
                         unsigned int* __restrict__ POOL) {
    const int w = threadIdx.x >> 6, o = threadIdx.x & 63;
    const int nw = GRID * 4;
    const float bo = bias[o];
    for (int n0 = blockIdx.x * 4 + w; n0 < N_NODES; n0 += nw) {
        int n = __builtin_amdgcn_readfirstlane(n0);
        float s = AGG[n * EMB + o] + bo;
        if (ZAGG) AGG[n * EMB + o] = 0.f;
        const float* xr = xin + (size_t)n * IN;       // wave-uniform -> scalar loads
#pragma unroll
        for (int i = 0; i < IN; i++) s += xr[i] * root[i * EMB + o];
        s = fmaxf(s, 0.f);
        Xout[n * EMB + o] = s;
        if (WBF) Xbf[n * EMB + o] = f2b(s);
        if (POOLING) atomicMax(&POOL[batch[n] * EMB + o], __float_as_uint(s));
    }
}

// --- Stage: head (block 0 only). out[g] = (pooled[g]@l0w + l0b) @ l1w + l1b
__device__ void d_head(const float* __restrict__ POOLf,
                       const float* __restrict__ l0w, const float* __restrict__ l0b,
                       const float* __restrict__ l1w, const float* __restrict__ l1b,
                       float* __restrict__ out) {
    __shared__ float P[NGRAPH * EMB];
    for (int i = threadIdx.x; i < NGRAPH * EMB; i += 256) P[i] = POOLf[i];
    __syncthreads();
    int g = threadIdx.x;
    if (g < NGRAPH) {
        float acc = l1b[0];
        for (int o2 = 0; o2 < EMB; o2++) {
            float h = l0b[o2];
            for (int o = 0; o < EMB; o++) h += P[g * EMB + o] * l0w[o * EMB + o2];
            acc += h * l1w[o2];
        }
        out[g] = acc;
    }
}

// ---------------------------------------------------------------------------
// Persistent mega-kernel: prep | (pre, gather, update) x3 | head, separated
// by grid barriers. Replaces 11 dispatches with 1 (+ tiny memset).
// ---------------------------------------------------------------------------
__global__ void __launch_bounds__(256, 4) mega(
    const float* x_p, const float* ea, const int* src, const int* dst, const int* batch,
    const float* nn0_w1, const float* nn0_b1, const float* nn0_w2, const float* nn0_b2,
    const float* nn1_w1, const float* nn1_b1, const float* nn1_w2, const float* nn1_b2,
    const float* root0, const float* bias0, const float* root1, const float* bias1,
    const float* root2, const float* bias2,
    const float* lin0_w, const float* lin0_b, const float* lin1_w, const float* lin1_b,
    float* out,
    float* A0, float* A1, unsigned short* W2p0, unsigned short* W2p1,
    unsigned short* Xbf0, unsigned short* XbfB, unsigned short* U, float* XB,
    float* X, float* POOLf, unsigned int* bar) {
    unsigned int ph = 0;
    unsigned int* POOLu = (unsigned int*)POOLf;

    d_prep(ea, nn0_w1, nn0_b1, nn1_w1, nn1_b1, A0, A1, x_p, Xbf0,
           nn0_w2, nn0_b2, W2p0, nn1_w2, nn1_b2, W2p1, XbfB, /*AGG=*/X + 0, POOLf);
    // NOTE: AGG aliasing trick not used — AGG passed explicitly below via X? No:
    // AGG is its own buffer; see launch wrapper. (X here is X buffer.)
    // -- the real AGG pointer is threaded through the wrapper; placeholder removed.
    ph++; gsync(bar, ph * GRID);
    // (stages continue in wrapper-provided order below)
    // conv 0
    d_pre<F_NODE>(Xbf0, W2p0, U, XB);
    ph++; gsync(bar, ph * GRID);
    d_gather(A0, U, XB, src, dst, /*AGG*/ X);          // placeholder, fixed below
    ph++; gsync(bar, ph * GRID);
    (void)0;
    // This body is replaced by mega2 below.
}

// The actual kernel (clean version with explicit AGG buffer).
__global__ void __launch_bounds__(256, 4) mega2(
    const float* x_p, const float* ea, const int* src, const int* dst, const int* batch,
    const float* nn0_w1, const float* nn0_b1, const float* nn0_w2, const float* nn0_b2,
    const float* nn1_w1, const float* nn1_b1, const float* nn1_w2, const float* nn1_b2,
    const float* root0, const float* bias0, const float* root1, const float* bias1,
    const float* root2, const float* bias2,
    const float* lin0_w, const float* lin0_b, const float* lin1_w, const float* lin1_b,
    float* out,
    float* A0, float* A1, unsigned short* W2p0, unsigned short* W2p1,
    unsigned short* Xbf0, unsigned short* XbfB, unsigned short* U, float* XB,
    float* X, float* AGG, float* POOLf, unsigned int* bar) {
    unsigned int ph = 0;
    unsigned int* POOLu = (unsigned int*)POOLf;

    d_prep(ea, nn0_w1, nn0_b1, nn1_w1, nn1_b1, A0, A1, x_p, Xbf0,
           nn0_w2, nn0_b2, W2p0, nn1_w2, nn1_b2, W2p1, XbfB, AGG, POOLf);
    ph++; gsync(bar, ph * GRID);

    // ---- conv 0 (K = 32)
    d_pre<F_NODE>(Xbf0, W2p0, U, XB);
    ph++; gsync(bar, ph * GRID);
    d_gather(A0, U, XB, src, dst, AGG);
    ph++; gsync(bar, ph * GRID);
    d_update<F_NODE, false, true, true>(x_p, AGG, root0, bias0, batch, X, XbfB, POOLu);
    ph++; gsync(bar, ph * GRID);

    // ---- conv 1 (K = 64)
    d_pre<EMB>(XbfB, W2p1, U, XB);
    ph++; gsync(bar, ph * GRID);
    d_gather(A1, U, XB, src, dst, AGG);
    ph++; gsync(bar, ph * GRID);
    d_update<EMB, false, true, true>(X, AGG, root1, bias1, batch, X, XbfB, POOLu);
    ph++; gsync(bar, ph * GRID);

    // ---- conv 2 (K = 64, pooled)
    d_pre<EMB>(XbfB, W2p1, U, XB);
    ph++; gsync(bar, ph * GRID);
    d_gather(A1, U, XB, src, dst, AGG);
    ph++; gsync(bar, ph * GRID);
    d_update<EMB, true, false, false>(X, AGG, root2, bias2, batch, X, XbfB, POOLu);
    ph++; gsync(bar, ph * GRID);

    if (blockIdx.x == 0)
        d_head(POOLf, lin0_w, lin0_b, lin1_w, lin1_b, out);
}

extern "C" void kernel_launch(void* const* d_in, const int* in_sizes, int n_in,
                              void* d_out, int out_size, void* d_ws, size_t ws_size,
                              hipStream_t stream) {
    const float* x_p    = (const float*)d_in[0];
    const float* ea     = (const float*)d_in[2];
    const int*   eidx   = (const int*)d_in[4];
    const int*   batch  = (const int*)d_in[5];
    const float* nn0_w1 = (const float*)d_in[6];
    const float* nn0_b1 = (const float*)d_in[7];
    const float* nn0_w2 = (const float*)d_in[8];
    const float* nn0_b2 = (const float*)d_in[9];
    const float* nn1_w1 = (const float*)d_in[10];
    const float* nn1_b1 = (const float*)d_in[11];
    const float* nn1_w2 = (const float*)d_in[12];
    const float* nn1_b2 = (const float*)d_in[13];
    const float* root0  = (const float*)d_in[14];
    const float* bias0  = (const float*)d_in[15];
    const float* root1  = (const float*)d_in[16];
    const float* bias1  = (const float*)d_in[17];
    const float* root2  = (const float*)d_in[18];
    const float* bias2  = (const float*)d_in[19];
    const float* lin0_w = (const float*)d_in[20];
    const float* lin0_b = (const float*)d_in[21];
    const float* lin1_w = (const float*)d_in[22];
    const float* lin1_b = (const float*)d_in[23];

    const int* src = eidx;             // edge_index_p[0]
    const int* dst = eidx + N_EDGES;   // edge_index_p[1]

    // workspace layout (~34 MB); bar first so one tiny memset clears it
    char* ws = (char*)d_ws;
    unsigned int* bar    = (unsigned int*)ws;   ws += 256;
    float* A0            = (float*)ws;          ws += (size_t)N_EDGES * HID * 4;
    float* A1            = (float*)ws;          ws += (size_t)N_EDGES * HID * 4;
    unsigned short* W2p0 = (unsigned short*)ws; ws += (size_t)NCOL * F_NODE * 2;
    unsigned short* W2p1 = (unsigned short*)ws; ws += (size_t)NCOL * EMB * 2;
    unsigned short* Xbf0 = (unsigned short*)ws; ws += (size_t)M_PAD * F_NODE * 2;
    unsigned short* XbfB = (unsigned short*)ws; ws += (size_t)M_PAD * EMB * 2;
    unsigned short* U    = (unsigned short*)ws; ws += (size_t)M_PAD * 1024 * 2;
    float* XB            = (float*)ws;          ws += (size_t)M_PAD * EMB * 4;
    float* X             = (float*)ws;          ws += (size_t)N_NODES * EMB * 4;
    float* AGG           = (float*)ws;          ws += (size_t)N_NODES * EMB * 4;
    float* POOLf         = (float*)ws;          ws += (size_t)NGRAPH * EMB * 4;

    hipMemsetAsync(bar, 0, 256, stream);
    mega2<<<GRID, 256, 0, stream>>>(
        x_p, ea, src, dst, batch,
        nn0_w1, nn0_b1, nn0_w2, nn0_b2, nn1_w1, nn1_b1, nn1_w2, nn1_b2,
        root0, bias0, root1, bias1, root2, bias2,
        lin0_w, lin0_b, lin1_w, lin1_b,
        (float*)d_out,
        A0, A1, W2p0, W2p1, Xbf0, XbfB, U, XB, X, AGG, POOLf, bar);
}

// Round 5
// 846.246 us; speedup vs baseline: 1.8888x; 1.8888x over previous
//
#include <hip/hip_runtime.h>
#include <hip/hip_bf16.h>
#include <hip/hip_cooperative_groups.h>

namespace cg = cooperative_groups;

#define N_NODES 10000
#define N_EDGES 30000
#define F_NODE  32
#define F_EDGE  8
#define EMB     64
#define HID     16
#define NGRAPH  64

#define M_PAD   10016             // 626 * 16 (GEMM row padding)
#define NCOL    1088              // 1024 U columns + 64 XB columns
#define GRID    512               // proven co-resident (round 2); launch_bounds(256,4) => capacity 1024

typedef __attribute__((ext_vector_type(8))) short short8;   // 8 bf16 (MFMA A/B frag)
typedef __attribute__((ext_vector_type(4))) float f32x4;    // MFMA C/D frag

__device__ __forceinline__ unsigned short f2b(float f) {
    __hip_bfloat16 h = __float2bfloat16(f);
    return __builtin_bit_cast(unsigned short, h);
}

// All pointers in one struct so the cooperative launch takes a single kernarg.
struct Params {
    const float *x_p, *ea;
    const int *src, *dst, *batch;
    const float *nn0_w1, *nn0_b1, *nn0_w2, *nn0_b2;
    const float *nn1_w1, *nn1_b1, *nn1_w2, *nn1_b2;
    const float *root0, *bias0, *root1, *bias1, *root2, *bias2;
    const float *lin0_w, *lin0_b, *lin1_w, *lin1_b;
    float* out;
    float *A0, *A1;
    unsigned short *W2p0, *W2p1, *Xbf0, *XbfB, *U;
    float *XB, *X, *AGG, *POOLf;
};

// ---------------------------------------------------------------------------
// Stage: prep. Edge-MLP hiddens (both MLPs), x_p->bf16 (pad zeroed), permuted
// bf16 weights W2p[j=o*16+h][k] (+ b2 appended as cols 1024..1087), XbfB pad
// zero, AGG zero (conv0), POOL zero.   (grid-stride; any grid size)
// ---------------------------------------------------------------------------
__device__ void d_prep(const Params& p) {
    const int gtid = blockIdx.x * 256 + threadIdx.x;
    const int nthr = gridDim.x * 256;
    for (int e = gtid; e < N_EDGES; e += nthr) {       // edge MLP hidden layers
        float f[F_EDGE];
#pragma unroll
        for (int i = 0; i < F_EDGE; i++) f[i] = p.ea[e * F_EDGE + i];
#pragma unroll
        for (int h = 0; h < HID; h++) {
            float s0 = p.nn0_b1[h], s1 = p.nn1_b1[h];
#pragma unroll
            for (int i = 0; i < F_EDGE; i++) {
                s0 += f[i] * p.nn0_w1[i * HID + h];
                s1 += f[i] * p.nn1_w1[i * HID + h];
            }
            p.A0[e * HID + h] = fmaxf(s0, 0.f);
            p.A1[e * HID + h] = fmaxf(s1, 0.f);
        }
    }
    for (int i = gtid; i < M_PAD * F_NODE; i += nthr)  // x_p -> bf16, pad rows zero
        p.Xbf0[i] = (i < N_NODES * F_NODE) ? f2b(p.x_p[i]) : (unsigned short)0;
    for (int i = gtid; i < NCOL * F_NODE; i += nthr) { // W2p0 (K=32)
        int j = i >> 5, k = i & 31;
        float v = (j < 1024) ? p.nn0_w2[(j & 15) * (F_NODE * EMB) + k * EMB + (j >> 4)]
                             : p.nn0_b2[k * EMB + (j - 1024)];
        p.W2p0[i] = f2b(v);
    }
    for (int i = gtid; i < NCOL * EMB; i += nthr) {    // W2p1 (K=64)
        int j = i >> 6, k = i & 63;
        float v = (j < 1024) ? p.nn1_w2[(j & 15) * (EMB * EMB) + k * EMB + (j >> 4)]
                             : p.nn1_b2[k * EMB + (j - 1024)];
        p.W2p1[i] = f2b(v);
    }
    for (int i = gtid; i < (M_PAD - N_NODES) * EMB; i += nthr)
        p.XbfB[N_NODES * EMB + i] = 0;                 // XbfB pad rows
    for (int i = gtid; i < N_NODES * EMB; i += nthr) p.AGG[i] = 0.f;
    for (int i = gtid; i < NGRAPH * EMB; i += nthr) p.POOLf[i] = 0.f;
}

// ---------------------------------------------------------------------------
// Stage: MFMA precompute. C[M_PAD x 1088] = Xbf @ W2p^T, K = 32 or 64.
//   cols < 1024 -> U[n][o*16+h] bf16 ; cols >= 1024 -> XB[n][o] fp32
// 16-row groups (626 total), grid-stride; 4 waves x 17 col-tiles per group.
// ---------------------------------------------------------------------------
template <int K>
__device__ void d_pre(const unsigned short* __restrict__ Xbf,
                      const unsigned short* __restrict__ W2p,
                      unsigned short* __restrict__ U, float* __restrict__ XB) {
    const int t = threadIdx.x;
    const int w = t >> 6, l = t & 63;
    const int lrow = l & 15;
    const int lk = (l >> 4) * 8;
    for (int g = blockIdx.x; g < M_PAD / 16; g += gridDim.x) {
        const int n0 = g * 16;
        short8 a[K / 32];
#pragma unroll
        for (int kk = 0; kk < K / 32; kk++)
            a[kk] = *reinterpret_cast<const short8*>(
                Xbf + (size_t)(n0 + lrow) * K + kk * 32 + lk);
        for (int ct = 0; ct < 17; ct++) {
            int c0 = (w * 17 + ct) * 16;
            short8 bf[K / 32];
#pragma unroll
            for (int kk = 0; kk < K / 32; kk++)
                bf[kk] = *reinterpret_cast<const short8*>(
                    W2p + (size_t)(c0 + lrow) * K + kk * 32 + lk);
            f32x4 acc = {0.f, 0.f, 0.f, 0.f};
#pragma unroll
            for (int kk = 0; kk < K / 32; kk++)
                acc = __builtin_amdgcn_mfma_f32_16x16x32_bf16(a[kk], bf[kk], acc, 0, 0, 0);
            int r0 = n0 + (l >> 4) * 4;     // D: row=(l>>4)*4+r, col=l&15
            int col = c0 + lrow;
            if (c0 < 1024) {
#pragma unroll
                for (int r = 0; r < 4; r++)
                    U[(size_t)(r0 + r) * 1024 + col] = f2b(acc[r]);
            } else {
#pragma unroll
                for (int r = 0; r < 4; r++)
                    XB[(size_t)(r0 + r) * EMB + (col - 1024)] = acc[r];
            }
        }
    }
}

// ---------------------------------------------------------------------------
// Stage: gather. One wave per edge (grid-stride):
//   msg[e,o] = XB[s,o] + sum_h A[e,h]*U[s][o*16+h];  atomicAdd into AGG[d,o].
// ---------------------------------------------------------------------------
__device__ void d_gather(const float* __restrict__ A, const unsigned short* __restrict__ U,
                         const float* __restrict__ XB,
                         const int* __restrict__ src, const int* __restrict__ dst,
                         float* __restrict__ AGG) {
    const int w = threadIdx.x >> 6, o = threadIdx.x & 63;
    const int nw = gridDim.x * 4;
    for (int e0 = blockIdx.x * 4 + w; e0 < N_EDGES; e0 += nw) {
        int e = __builtin_amdgcn_readfirstlane(e0);
        int s = src[e], d = dst[e];
        const uint4* up = reinterpret_cast<const uint4*>(U + (size_t)s * 1024 + o * 16);
        uint4 u0 = up[0];
        uint4 u1 = up[1];
        const float* Ae = A + e * HID;          // wave-uniform address
        float a[HID];
#pragma unroll
        for (int h = 0; h < HID; h++) a[h] = Ae[h];
        float m = XB[s * EMB + o];
#define ACC2(wrd, h)                                                              \
        m = fmaf(__builtin_bit_cast(float, (unsigned)(wrd) << 16), a[h], m);      \
        m = fmaf(__builtin_bit_cast(float, (unsigned)(wrd) & 0xffff0000u), a[h + 1], m);
        ACC2(u0.x, 0) ACC2(u0.y, 2) ACC2(u0.z, 4) ACC2(u0.w, 6)
        ACC2(u1.x, 8) ACC2(u1.y, 10) ACC2(u1.z, 12) ACC2(u1.w, 14)
#undef ACC2
        atomicAdd(&AGG[(size_t)d * EMB + o], m);
    }
}

// ---------------------------------------------------------------------------
// Stage: node update. One wave per node (grid-stride). ZAGG re-zeros AGG for
// the next conv. In-place X update: NO __restrict__ on xin/Xout (they alias
// for convs 1/2; each wave reads only its own row before writing it).
// ---------------------------------------------------------------------------
template <int IN, bool POOLING, bool WBF, bool ZAGG>
__device__ void d_update(const float* xin, float* __restrict__ AGG,
                         const float* __restrict__ root, const float* __restrict__ bias,
                         const int* __restrict__ batch,
                         float* Xout, unsigned short* __restrict__ Xbf,
                         unsigned int* __restrict__ POOL) {
    const int w = threadIdx.x >> 6, o = threadIdx.x & 63;
    const int nw = gridDim.x * 4;
    const float bo = bias[o];
    for (int n0 = blockIdx.x * 4 + w; n0 < N_NODES; n0 += nw) {
        int n = __builtin_amdgcn_readfirstlane(n0);
        float s = AGG[n * EMB + o] + bo;
        if (ZAGG) AGG[n * EMB + o] = 0.f;
        const float* xr = xin + (size_t)n * IN;       // wave-uniform row
        float sv = s;
#pragma unroll
        for (int i = 0; i < IN; i++) sv += xr[i] * root[i * EMB + o];
        sv = fmaxf(sv, 0.f);
        Xout[n * EMB + o] = sv;
        if (WBF) Xbf[n * EMB + o] = f2b(sv);
        if (POOLING) atomicMax(&POOL[batch[n] * EMB + o], __float_as_uint(sv));
    }
}

// --- Stage: head. Block g (< 64), wave 0; lane o2 owns hidden unit o2.
__device__ void d_head(const Params& p) {
    if (blockIdx.x < NGRAPH && threadIdx.x < 64) {
        int g = blockIdx.x, o2 = threadIdx.x;
        float h = p.lin0_b[o2];
        for (int o = 0; o < EMB; o++) h += p.POOLf[g * EMB + o] * p.lin0_w[o * EMB + o2];
        float v = h * p.lin1_w[o2];
#pragma unroll
        for (int off = 32; off; off >>= 1) v += __shfl_down(v, off, 64);
        if (o2 == 0) p.out[g] = v + p.lin1_b[0];
    }
}

// ---------------------------------------------------------------------------
// Cooperative mega-kernel: prep | (pre, gather, update) x3 | head, separated
// by vendor grid barriers (cg::this_grid().sync() — validated for multi-XCD
// coherence, unlike round 3/4's hand-rolled spin which thrashed/hung).
// ---------------------------------------------------------------------------
__global__ void __launch_bounds__(256, 4) mega(Params p) {
    cg::grid_group grid = cg::this_grid();
    unsigned int* POOLu = (unsigned int*)p.POOLf;

    d_prep(p);
    grid.sync();

    // ---- conv 0 (K = 32)
    d_pre<F_NODE>(p.Xbf0, p.W2p0, p.U, p.XB);
    grid.sync();
    d_gather(p.A0, p.U, p.XB, p.src, p.dst, p.AGG);
    grid.sync();
    d_update<F_NODE, false, true, true>(p.x_p, p.AGG, p.root0, p.bias0, p.batch,
                                        p.X, p.XbfB, POOLu);
    grid.sync();

    // ---- conv 1 (K = 64)
    d_pre<EMB>(p.XbfB, p.W2p1, p.U, p.XB);
    grid.sync();
    d_gather(p.A1, p.U, p.XB, p.src, p.dst, p.AGG);
    grid.sync();
    d_update<EMB, false, true, true>(p.X, p.AGG, p.root1, p.bias1, p.batch,
                                     p.X, p.XbfB, POOLu);
    grid.sync();

    // ---- conv 2 (K = 64, pooled)
    d_pre<EMB>(p.XbfB, p.W2p1, p.U, p.XB);
    grid.sync();
    d_gather(p.A1, p.U, p.XB, p.src, p.dst, p.AGG);
    grid.sync();
    d_update<EMB, true, false, false>(p.X, p.AGG, p.root2, p.bias2, p.batch,
                                      p.X, p.XbfB, POOLu);
    grid.sync();

    d_head(p);
}

// ---------------------------------------------------------------------------
// Fallback pipeline (plain dispatches) in case cooperative launch is refused.
// Same device stages; 11 dispatches ≈ round-1 performance (236 µs), not a
// dead round.
// ---------------------------------------------------------------------------
__global__ void __launch_bounds__(256) k_prep_w(Params p) { d_prep(p); }
template <int K>
__global__ void __launch_bounds__(256) k_pre_w(Params p) {
    if constexpr (K == F_NODE) d_pre<F_NODE>(p.Xbf0, p.W2p0, p.U, p.XB);
    else                       d_pre<EMB>(p.XbfB, p.W2p1, p.U, p.XB);
}
template <int CONV>
__global__ void __launch_bounds__(256) k_gather_w(Params p) {
    d_gather(CONV == 0 ? p.A0 : p.A1, p.U, p.XB, p.src, p.dst, p.AGG);
}
template <int CONV>
__global__ void __launch_bounds__(256) k_update_w(Params p) {
    unsigned int* POOLu = (unsigned int*)p.POOLf;
    if constexpr (CONV == 0)
        d_update<F_NODE, false, true, true>(p.x_p, p.AGG, p.root0, p.bias0, p.batch,
                                            p.X, p.XbfB, POOLu);
    else if constexpr (CONV == 1)
        d_update<EMB, false, true, true>(p.X, p.AGG, p.root1, p.bias1, p.batch,
                                         p.X, p.XbfB, POOLu);
    else
        d_update<EMB, true, false, false>(p.X, p.AGG, p.root2, p.bias2, p.batch,
                                          p.X, p.XbfB, POOLu);
}
__global__ void k_head_w(Params p) { d_head(p); }

extern "C" void kernel_launch(void* const* d_in, const int* in_sizes, int n_in,
                              void* d_out, int out_size, void* d_ws, size_t ws_size,
                              hipStream_t stream) {
    Params p;
    p.x_p    = (const float*)d_in[0];
    p.ea     = (const float*)d_in[2];
    const int* eidx = (const int*)d_in[4];
    p.src    = eidx;                   // edge_index_p[0]
    p.dst    = eidx + N_EDGES;         // edge_index_p[1]
    p.batch  = (const int*)d_in[5];
    p.nn0_w1 = (const float*)d_in[6];  p.nn0_b1 = (const float*)d_in[7];
    p.nn0_w2 = (const float*)d_in[8];  p.nn0_b2 = (const float*)d_in[9];
    p.nn1_w1 = (const float*)d_in[10]; p.nn1_b1 = (const float*)d_in[11];
    p.nn1_w2 = (const float*)d_in[12]; p.nn1_b2 = (const float*)d_in[13];
    p.root0  = (const float*)d_in[14]; p.bias0  = (const float*)d_in[15];
    p.root1  = (const float*)d_in[16]; p.bias1  = (const float*)d_in[17];
    p.root2  = (const float*)d_in[18]; p.bias2  = (const float*)d_in[19];
    p.lin0_w = (const float*)d_in[20]; p.lin0_b = (const float*)d_in[21];
    p.lin1_w = (const float*)d_in[22]; p.lin1_b = (const float*)d_in[23];
    p.out    = (float*)d_out;

    // workspace layout (~34 MB)
    char* ws = (char*)d_ws;
    p.A0   = (float*)ws;          ws += (size_t)N_EDGES * HID * 4;
    p.A1   = (float*)ws;          ws += (size_t)N_EDGES * HID * 4;
    p.W2p0 = (unsigned short*)ws; ws += (size_t)NCOL * F_NODE * 2;
    p.W2p1 = (unsigned short*)ws; ws += (size_t)NCOL * EMB * 2;
    p.Xbf0 = (unsigned short*)ws; ws += (size_t)M_PAD * F_NODE * 2;
    p.XbfB = (unsigned short*)ws; ws += (size_t)M_PAD * EMB * 2;
    p.U    = (unsigned short*)ws; ws += (size_t)M_PAD * 1024 * 2;
    p.XB   = (float*)ws;          ws += (size_t)M_PAD * EMB * 4;
    p.X    = (float*)ws;          ws += (size_t)N_NODES * EMB * 4;
    p.AGG  = (float*)ws;          ws += (size_t)N_NODES * EMB * 4;
    p.POOLf = (float*)ws;         ws += (size_t)NGRAPH * EMB * 4;

    void* kargs[] = { (void*)&p };
    hipError_t err = hipLaunchCooperativeKernel(mega, dim3(GRID), dim3(256),
                                                kargs, 0, stream);
    if (err != hipSuccess) {
        (void)hipGetLastError();       // clear sticky error; run plain pipeline
        k_prep_w<<<GRID, 256, 0, stream>>>(p);
        k_pre_w<F_NODE><<<GRID, 256, 0, stream>>>(p);
        k_gather_w<0><<<GRID, 256, 0, stream>>>(p);
        k_update_w<0><<<GRID, 256, 0, stream>>>(p);
        k_pre_w<EMB><<<GRID, 256, 0, stream>>>(p);
        k_gather_w<1><<<GRID, 256, 0, stream>>>(p);
        k_update_w<1><<<GRID, 256, 0, stream>>>(p);
        k_pre_w<EMB><<<GRID, 256, 0, stream>>>(p);
        k_gather_w<2><<<GRID, 256, 0, stream>>>(p);
        k_update_w<2><<<GRID, 256, 0, stream>>>(p);
        k_head_w<<<NGRAPH, 64, 0, stream>>>(p);
    }
}

// Round 6
// 260.262 us; speedup vs baseline: 6.1415x; 3.2515x over previous
//
#include <hip/hip_runtime.h>
#include <hip/hip_bf16.h>

#define N_NODES 10000
#define N_EDGES 30000
#define F_NODE  32
#define F_EDGE  8
#define EMB     64
#define HID     16
#define NGRAPH  64
#define NBUCK   625              // 10000/16 exact -> no row padding anywhere
#define NCOL    1088             // 1024 U cols + 64 XB cols

typedef __attribute__((ext_vector_type(8))) short short8;   // 8 bf16 (MFMA A/B frag)
typedef __attribute__((ext_vector_type(4))) float f32x4;    // MFMA C/D frag

__device__ __forceinline__ unsigned short f2b(float f) {
    __hip_bfloat16 h = __float2bfloat16(f);
    return __builtin_bit_cast(unsigned short, h);
}

struct P {
    const float *x_p, *ea;
    const int *src, *dst, *batch;
    const float *nn0_w1, *nn0_b1, *nn0_w2, *nn0_b2;
    const float *nn1_w1, *nn1_b1, *nn1_w2, *nn1_b2;
    const float *root0, *bias0, *root1, *bias1, *root2, *bias2;
    const float *lin0_w, *lin0_b, *lin1_w, *lin1_b;
    float *out;
    int *bucketCnt, *bucketPtr, *cursor, *ebuf;
    float *A0, *A1;
    unsigned short *W2p0, *W2p1;
    float *AGGa, *AGGb, *X0, *X1, *POOL;
};

// ---------------------------------------------------------------------------
// prep (heterogeneous blocks): edge-MLP hiddens A0/A1 + src-bucket histogram;
// permuted bf16 weights W2p[j=o*16+h][k] with b2 appended as cols 1024..1087.
// grid = 118 (edges) + 136 (W2p0) + 272 (W2p1) = 526
// ---------------------------------------------------------------------------
__global__ void __launch_bounds__(256) k_prep(P p) {
    int b = blockIdx.x, t = threadIdx.x;
    if (b < 118) {
        int e = b * 256 + t;
        if (e >= N_EDGES) return;
        float f[F_EDGE];
#pragma unroll
        for (int i = 0; i < F_EDGE; i++) f[i] = p.ea[e * F_EDGE + i];
#pragma unroll
        for (int h = 0; h < HID; h++) {
            float s0 = p.nn0_b1[h], s1 = p.nn1_b1[h];
#pragma unroll
            for (int i = 0; i < F_EDGE; i++) {
                s0 += f[i] * p.nn0_w1[i * HID + h];
                s1 += f[i] * p.nn1_w1[i * HID + h];
            }
            p.A0[e * HID + h] = fmaxf(s0, 0.f);
            p.A1[e * HID + h] = fmaxf(s1, 0.f);
        }
        atomicAdd(&p.bucketCnt[p.src[e] >> 4], 1);
    } else if (b < 254) {                       // W2p0 (K=32): 34816 elems
        int i = (b - 118) * 256 + t;
        if (i >= NCOL * F_NODE) return;
        int j = i >> 5, k = i & 31;
        float v = (j < 1024) ? p.nn0_w2[(j & 15) * (F_NODE * EMB) + k * EMB + (j >> 4)]
                             : p.nn0_b2[k * EMB + (j - 1024)];
        p.W2p0[i] = f2b(v);
    } else {                                    // W2p1 (K=64): 69632 elems
        int i = (b - 254) * 256 + t;
        if (i >= NCOL * EMB) return;
        int j = i >> 6, k = i & 63;
        float v = (j < 1024) ? p.nn1_w2[(j & 15) * (EMB * EMB) + k * EMB + (j >> 4)]
                             : p.nn1_b2[k * EMB + (j - 1024)];
        p.W2p1[i] = f2b(v);
    }
}

// --- exclusive scan of 625 bucket counts (one block) -> bucketPtr, cursor
__global__ void __launch_bounds__(1024) k_scan(P p) {
    __shared__ int sc[1024];
    int t = threadIdx.x;
    int c = (t < NBUCK) ? p.bucketCnt[t] : 0;
    sc[t] = c;
    __syncthreads();
    for (int off = 1; off < 1024; off <<= 1) {
        int v = (t >= off) ? sc[t - off] : 0;
        __syncthreads();
        sc[t] += v;
        __syncthreads();
    }
    if (t < NBUCK) { p.bucketPtr[t + 1] = sc[t]; p.cursor[t] = sc[t] - c; }
    if (t == 0) p.bucketPtr[0] = 0;
}

// --- scatter edge ids into src-buckets
__global__ void __launch_bounds__(256) k_scatter(P p) {
    int e = blockIdx.x * 256 + threadIdx.x;
    if (e >= N_EDGES) return;
    int pos = atomicAdd(&p.cursor[p.src[e] >> 4], 1);
    p.ebuf[pos] = e;
}

// ---------------------------------------------------------------------------
// Fused conv kernel, block b owns nodes [16b, 16b+16):
//   CONV>0 prologue: X_{c-1} rows from AGG+root+bias (own rows only; writes
//     X0/X1 global for later consumers; conv1 re-zeros AGGa for conv2).
//   MFMA: U/XB tile -> LDS only (never global). U layout [row][h/2][o*2+h%2]
//     so edge reads are 8x stride-256B ds_read_b32 (conflict-free).
//   Edge loop: edges of this src-bucket; msg -> atomicAdd AGG_out[dst].
// AGG ping-pong: conv0 -> AGGa, conv1 -> AGGb, conv2 -> AGGa (zeroed by
// conv1 prologue). Prologue reads and edge atomics never share a buffer
// within one dispatch.
// ---------------------------------------------------------------------------
template <int CONV>
__global__ void __launch_bounds__(256) k_fused(P p) {
    constexpr int K = (CONV == 0) ? F_NODE : EMB;
    __shared__ unsigned short U_lds[16][8][128];   // 32 KB  [row][h>>1][o*2+(h&1)]
    __shared__ float XB_lds[16][64];               // 4 KB
    __shared__ float Xt[16][65];                   // 4.1 KB (pad 65: bank-spread)
    const int b = blockIdx.x, t = threadIdx.x;
    const int n0 = b * 16;
    const int w = t >> 6, l = t & 63;
    const int lrow = l & 15, lk4 = l >> 4;

    if (CONV > 0) {      // prologue: previous conv's node update for own rows
        const float* aggIn = (CONV == 1) ? p.AGGa : p.AGGb;
        const float* rt = (CONV == 1) ? p.root0 : p.root1;
        const float* bs = (CONV == 1) ? p.bias0 : p.bias1;
        constexpr int IN = (CONV == 1) ? F_NODE : EMB;
        for (int idx = t; idx < 16 * 64; idx += 256) {
            int j = idx >> 6, o = idx & 63;
            int n = n0 + j;
            float s = aggIn[n * EMB + o] + bs[o];
            const float* xr = (CONV == 1) ? (p.x_p + (size_t)n * IN)
                                          : (p.X0 + (size_t)n * IN);
#pragma unroll
            for (int i = 0; i < IN; i++) s += xr[i] * rt[i * EMB + o];
            float sv = fmaxf(s, 0.f);
            Xt[j][o] = sv;
            if (CONV == 1) { p.X0[n * EMB + o] = sv; p.AGGa[n * EMB + o] = 0.f; }
            else           { p.X1[n * EMB + o] = sv; }
        }
        __syncthreads();
    }

    // ---- MFMA: C[16 x 1088] = X_tile @ W2p^T
    short8 afr[K / 32];
    if (CONV == 0) {
        const float* xp = p.x_p + (size_t)(n0 + lrow) * F_NODE + lk4 * 8;
#pragma unroll
        for (int q = 0; q < 8; q++) afr[0][q] = (short)f2b(xp[q]);
    } else {
#pragma unroll
        for (int kk = 0; kk < K / 32; kk++)
#pragma unroll
            for (int q = 0; q < 8; q++)
                afr[kk][q] = (short)f2b(Xt[lrow][kk * 32 + lk4 * 8 + q]);
    }
    const unsigned short* W2p = (CONV == 0) ? p.W2p0 : p.W2p1;
    for (int ct = 0; ct < 17; ct++) {
        int c0 = (w * 17 + ct) * 16;
        short8 bfr[K / 32];
#pragma unroll
        for (int kk = 0; kk < K / 32; kk++)
            bfr[kk] = *reinterpret_cast<const short8*>(
                W2p + (size_t)(c0 + lrow) * K + kk * 32 + lk4 * 8);
        f32x4 acc = {0.f, 0.f, 0.f, 0.f};
#pragma unroll
        for (int kk = 0; kk < K / 32; kk++)
            acc = __builtin_amdgcn_mfma_f32_16x16x32_bf16(afr[kk], bfr[kk], acc, 0, 0, 0);
        int rr = lk4 * 4;                    // D: row=(l>>4)*4+r, col=l&15
        int col = c0 + lrow;
        if (c0 < 1024) {
            int oo = col >> 4, hh = col & 15;
#pragma unroll
            for (int r = 0; r < 4; r++)
                U_lds[rr + r][hh >> 1][oo * 2 + (hh & 1)] = f2b(acc[r]);
        } else {
#pragma unroll
            for (int r = 0; r < 4; r++)
                XB_lds[rr + r][col - 1024] = acc[r];
        }
    }
    __syncthreads();

    // ---- edge loop over this block's src-bucket
    const float* Aarr = (CONV == 0) ? p.A0 : p.A1;
    float* aggOut = (CONV == 1) ? p.AGGb : p.AGGa;
    const int beg = p.bucketPtr[b], end = p.bucketPtr[b + 1];
    const int o = l;
    for (int q = beg + w; q < end; q += 4) {
        int e = __builtin_amdgcn_readfirstlane(p.ebuf[q]);
        int sloc = p.src[e] - n0;            // in [0,16)
        const float* Ae = Aarr + (size_t)e * HID;   // wave-uniform -> s_loads
        float av[HID];
#pragma unroll
        for (int h = 0; h < HID; h++) av[h] = Ae[h];
        const unsigned* up = reinterpret_cast<const unsigned*>(&U_lds[sloc][0][0]) + o;
        float m = XB_lds[sloc][o];
#define ACC2(wrd, h)                                                              \
        m = fmaf(__builtin_bit_cast(float, (unsigned)(wrd) << 16), av[h], m);     \
        m = fmaf(__builtin_bit_cast(float, (unsigned)(wrd) & 0xffff0000u), av[h + 1], m);
#pragma unroll
        for (int hh = 0; hh < 8; hh++) {
            unsigned uw = up[hh * 64];       // ds_read_b32, stride 256 B
            ACC2(uw, 2 * hh)
        }
#undef ACC2
        atomicAdd(&aggOut[(size_t)p.dst[e] * EMB + o], m);
    }
}

// --- conv2 node update + global max pool (no X store needed; only POOL used)
__global__ void __launch_bounds__(256) k_upd2(P p) {
    int w = threadIdx.x >> 6, o = threadIdx.x & 63;
    int n = __builtin_amdgcn_readfirstlane(blockIdx.x * 4 + w);
    float s = p.AGGa[n * EMB + o] + p.bias2[o];
    const float* xr = p.X1 + (size_t)n * EMB;    // wave-uniform row -> s_loads
#pragma unroll
    for (int i = 0; i < EMB; i++) s += xr[i] * p.root2[i * EMB + o];
    s = fmaxf(s, 0.f);
    atomicMax((unsigned*)&p.POOL[p.batch[n] * EMB + o], __float_as_uint(s));
}

// --- head: block g, lane o2: h[g,o2] then shuffle-reduce h·lin1_w
__global__ void k_head(P p) {
    int g = blockIdx.x, o2 = threadIdx.x;        // 64 blocks x 64 threads
    float h = p.lin0_b[o2];
    const float* Pg = p.POOL + g * EMB;
    for (int o = 0; o < EMB; o++) h += Pg[o] * p.lin0_w[o * EMB + o2];
    float v = h * p.lin1_w[o2];
#pragma unroll
    for (int off = 32; off; off >>= 1) v += __shfl_down(v, off, 64);
    if (o2 == 0) p.out[g] = v + p.lin1_b[0];
}

extern "C" void kernel_launch(void* const* d_in, const int* in_sizes, int n_in,
                              void* d_out, int out_size, void* d_ws, size_t ws_size,
                              hipStream_t stream) {
    P p;
    p.x_p    = (const float*)d_in[0];
    p.ea     = (const float*)d_in[2];
    const int* eidx = (const int*)d_in[4];
    p.src    = eidx;                   // edge_index_p[0]
    p.dst    = eidx + N_EDGES;         // edge_index_p[1]
    p.batch  = (const int*)d_in[5];
    p.nn0_w1 = (const float*)d_in[6];  p.nn0_b1 = (const float*)d_in[7];
    p.nn0_w2 = (const float*)d_in[8];  p.nn0_b2 = (const float*)d_in[9];
    p.nn1_w1 = (const float*)d_in[10]; p.nn1_b1 = (const float*)d_in[11];
    p.nn1_w2 = (const float*)d_in[12]; p.nn1_b2 = (const float*)d_in[13];
    p.root0  = (const float*)d_in[14]; p.bias0  = (const float*)d_in[15];
    p.root1  = (const float*)d_in[16]; p.bias1  = (const float*)d_in[17];
    p.root2  = (const float*)d_in[18]; p.bias2  = (const float*)d_in[19];
    p.lin0_w = (const float*)d_in[20]; p.lin0_b = (const float*)d_in[21];
    p.lin1_w = (const float*)d_in[22]; p.lin1_b = (const float*)d_in[23];
    p.out    = (float*)d_out;

    // workspace (~14.5 MB). Zero-region first -> one small memset:
    //   bucketCnt (4 KB pad) | AGGa | AGGb | POOL
    char* ws = (char*)d_ws;
    p.bucketCnt = (int*)ws;
    p.AGGa  = (float*)(ws + 4096);
    p.AGGb  = p.AGGa + (size_t)N_NODES * EMB;
    p.POOL  = p.AGGb + (size_t)N_NODES * EMB;
    const size_t ZBYTES = 4096 + ((size_t)2 * N_NODES * EMB + NGRAPH * EMB) * 4;
    char* w2 = ws + ZBYTES;
    p.A0   = (float*)w2;           w2 += (size_t)N_EDGES * HID * 4;
    p.A1   = (float*)w2;           w2 += (size_t)N_EDGES * HID * 4;
    p.W2p0 = (unsigned short*)w2;  w2 += (size_t)NCOL * F_NODE * 2;
    p.W2p1 = (unsigned short*)w2;  w2 += (size_t)NCOL * EMB * 2;
    p.bucketPtr = (int*)w2;        w2 += 2560;   // 626 ints, padded
    p.cursor    = (int*)w2;        w2 += 2560;   // 625 ints, padded
    p.ebuf      = (int*)w2;        w2 += (size_t)N_EDGES * 4;
    p.X0   = (float*)w2;           w2 += (size_t)N_NODES * EMB * 4;
    p.X1   = (float*)w2;           w2 += (size_t)N_NODES * EMB * 4;

    hipMemsetAsync(p.bucketCnt, 0, ZBYTES, stream);
    k_prep<<<526, 256, 0, stream>>>(p);
    k_scan<<<1, 1024, 0, stream>>>(p);
    k_scatter<<<118, 256, 0, stream>>>(p);
    k_fused<0><<<NBUCK, 256, 0, stream>>>(p);
    k_fused<1><<<NBUCK, 256, 0, stream>>>(p);
    k_fused<2><<<NBUCK, 256, 0, stream>>>(p);
    k_upd2<<<2500, 256, 0, stream>>>(p);
    k_head<<<NGRAPH, 64, 0, stream>>>(p);
}

// Round 7
// 236.346 us; speedup vs baseline: 6.7630x; 1.1012x over previous
//
#include <hip/hip_runtime.h>
#include <hip/hip_bf16.h>

#define N_NODES 10000
#define N_EDGES 30000
#define F_NODE  32
#define F_EDGE  8
#define EMB     64
#define HID     16
#define NGRAPH  64
#define NBUCK   625              // 10000/16 exact
#define NCOL    1088             // 1024 U cols + 64 XB cols
#define ROWW    514              // U_lds row stride in words (514%32=2 -> bank spread)

typedef __attribute__((ext_vector_type(8))) short short8;   // 8 bf16 (MFMA A/B frag)
typedef __attribute__((ext_vector_type(4))) float f32x4;    // MFMA C/D frag

__device__ __forceinline__ unsigned short f2b(float f) {
    __hip_bfloat16 h = __float2bfloat16(f);
    return __builtin_bit_cast(unsigned short, h);
}

struct P {
    const float *x_p, *ea;
    const int *src, *dst, *batch;
    const float *nn0_w1, *nn0_b1, *nn0_w2, *nn0_b2;
    const float *nn1_w1, *nn1_b1, *nn1_w2, *nn1_b2;
    const float *root0, *bias0, *root1, *bias1, *root2, *bias2;
    const float *lin0_w, *lin0_b, *lin1_w, *lin1_b;
    float *out;
    int *bucketCnt, *bucketPtr, *cursor, *metap;
    float *A0, *A1, *A0p, *A1p;
    unsigned short *W2p0, *W2p1;
    float *AGGa, *AGGb, *X0, *X1, *POOL;
};

// ---------------------------------------------------------------------------
// prep: edge-MLP hiddens A0/A1 + src-bucket histogram; permuted bf16 weights.
// W2p tile order (CONFLICT-FIX): tile T<64 holds {o=(T>>4)*16+lrow, h=T&15},
// i.e. within a tile the 16 lanes carry DIFFERENT o -> U_lds stores hit
// consecutive words. Tiles 64..67 are the b2 (XB) columns in plain order.
// grid = 118 (edges) + 136 (W2p0) + 272 (W2p1) = 526
// ---------------------------------------------------------------------------
__global__ void __launch_bounds__(256) k_prep(P p) {
    int b = blockIdx.x, t = threadIdx.x;
    if (b < 118) {
        int e = b * 256 + t;
        if (e >= N_EDGES) return;
        float f[F_EDGE];
#pragma unroll
        for (int i = 0; i < F_EDGE; i++) f[i] = p.ea[e * F_EDGE + i];
#pragma unroll
        for (int h = 0; h < HID; h++) {
            float s0 = p.nn0_b1[h], s1 = p.nn1_b1[h];
#pragma unroll
            for (int i = 0; i < F_EDGE; i++) {
                s0 += f[i] * p.nn0_w1[i * HID + h];
                s1 += f[i] * p.nn1_w1[i * HID + h];
            }
            p.A0[e * HID + h] = fmaxf(s0, 0.f);
            p.A1[e * HID + h] = fmaxf(s1, 0.f);
        }
        atomicAdd(&p.bucketCnt[p.src[e] >> 4], 1);
    } else if (b < 254) {                       // W2p0 (K=32): 34816 elems
        int i = (b - 118) * 256 + t;
        if (i >= NCOL * F_NODE) return;
        int rt = i >> 5, k = i & 31;
        float v;
        if (rt < 1024) {
            int T = rt >> 4, lr = rt & 15;
            int o = ((T >> 4) << 4) + lr, h = T & 15;
            v = p.nn0_w2[h * (F_NODE * EMB) + k * EMB + o];
        } else {
            v = p.nn0_b2[k * EMB + (rt - 1024)];
        }
        p.W2p0[i] = f2b(v);
    } else {                                    // W2p1 (K=64): 69632 elems
        int i = (b - 254) * 256 + t;
        if (i >= NCOL * EMB) return;
        int rt = i >> 6, k = i & 63;
        float v;
        if (rt < 1024) {
            int T = rt >> 4, lr = rt & 15;
            int o = ((T >> 4) << 4) + lr, h = T & 15;
            v = p.nn1_w2[h * (EMB * EMB) + k * EMB + o];
        } else {
            v = p.nn1_b2[k * EMB + (rt - 1024)];
        }
        p.W2p1[i] = f2b(v);
    }
}

// --- exclusive scan of 625 bucket counts (one block) -> bucketPtr, cursor
__global__ void __launch_bounds__(1024) k_scan(P p) {
    __shared__ int sc[1024];
    int t = threadIdx.x;
    int c = (t < NBUCK) ? p.bucketCnt[t] : 0;
    sc[t] = c;
    __syncthreads();
    for (int off = 1; off < 1024; off <<= 1) {
        int v = (t >= off) ? sc[t - off] : 0;
        __syncthreads();
        sc[t] += v;
        __syncthreads();
    }
    if (t < NBUCK) { p.bucketPtr[t + 1] = sc[t]; p.cursor[t] = sc[t] - c; }
    if (t == 0) p.bucketPtr[0] = 0;
}

// --- scatter: bucket-ordered edge meta (dst*16+sloc) + PERMUTED A rows so
//     the fused edge loop reads contiguous, dependency-free addresses.
__global__ void __launch_bounds__(256) k_scatter(P p) {
    int e = blockIdx.x * 256 + threadIdx.x;
    if (e >= N_EDGES) return;
    int s = p.src[e];
    int pos = atomicAdd(&p.cursor[s >> 4], 1);
    p.metap[pos] = p.dst[e] * 16 + (s & 15);
#pragma unroll
    for (int h = 0; h < HID; h++) {
        p.A0p[(size_t)pos * HID + h] = p.A0[(size_t)e * HID + h];
        p.A1p[(size_t)pos * HID + h] = p.A1[(size_t)e * HID + h];
    }
}

// ---------------------------------------------------------------------------
// Fused conv kernel, 512 threads (8 waves), block b owns nodes [16b,16b+16):
//   CONV>0 prologue: X_{c-1} rows from AGG+root+bias; conv1 re-zeros AGGa.
//   MFMA: U tile -> LDS only. U layout word = row*514 + (h>>1)*64 + o
//     (subword h&1). Writes conflict-free (transposed W2p tiles + row-stride
//     514); edge reads conflict-free (consecutive o).
//   Edge loop: bucket-ordered meta + A rows (contiguous s_loads, unroll 2);
//     msg -> atomicAdd AGG_out[dst].
// AGG ping-pong: conv0->AGGa, conv1->AGGb (zeroes AGGa), conv2->AGGa.
// ---------------------------------------------------------------------------
template <int CONV>
__global__ void __launch_bounds__(512) k_fused(P p) {
    constexpr int K = (CONV == 0) ? F_NODE : EMB;
    __shared__ unsigned short U2[16 * 2 * ROWW];   // 16 rows x 514 words = 32.9 KB
    __shared__ float XB_l[16][65];
    __shared__ float Xt[16][65];
    const int b = blockIdx.x, t = threadIdx.x;
    const int n0 = b * 16;
    const int w = t >> 6, l = t & 63;
    const int lrow = l & 15, lk4 = l >> 4;

    if (CONV > 0) {      // prologue: previous conv's node update for own rows
        const float* aggIn = (CONV == 1) ? p.AGGa : p.AGGb;
        const float* rt = (CONV == 1) ? p.root0 : p.root1;
        const float* bs = (CONV == 1) ? p.bias0 : p.bias1;
        constexpr int IN = (CONV == 1) ? F_NODE : EMB;
        for (int idx = t; idx < 16 * 64; idx += 512) {
            int j = idx >> 6, o = idx & 63;
            int n = n0 + j;
            float s = aggIn[n * EMB + o] + bs[o];
            const float* xr = (CONV == 1) ? (p.x_p + (size_t)n * IN)
                                          : (p.X0 + (size_t)n * IN);
#pragma unroll
            for (int i = 0; i < IN; i++) s += xr[i] * rt[i * EMB + o];
            float sv = fmaxf(s, 0.f);
            Xt[j][o] = sv;
            if (CONV == 1) { p.X0[n * EMB + o] = sv; p.AGGa[n * EMB + o] = 0.f; }
            else           { p.X1[n * EMB + o] = sv; }
        }
        __syncthreads();
    }

    // ---- MFMA: C[16 x 1088] = X_tile @ W2p^T  (tiles T = w + 8i)
    short8 afr[K / 32];
    if (CONV == 0) {
        const float* xp = p.x_p + (size_t)(n0 + lrow) * F_NODE + lk4 * 8;
#pragma unroll
        for (int q = 0; q < 8; q++) afr[0][q] = (short)f2b(xp[q]);
    } else {
#pragma unroll
        for (int kk = 0; kk < K / 32; kk++)
#pragma unroll
            for (int q = 0; q < 8; q++)
                afr[kk][q] = (short)f2b(Xt[lrow][kk * 32 + lk4 * 8 + q]);
    }
    const unsigned short* W2p = (CONV == 0) ? p.W2p0 : p.W2p1;
    for (int i = 0; i <= 8; i++) {
        int T = w + 8 * i;
        if (T >= 68) break;
        short8 bfr[K / 32];
#pragma unroll
        for (int kk = 0; kk < K / 32; kk++)
            bfr[kk] = *reinterpret_cast<const short8*>(
                W2p + (size_t)(T * 16 + lrow) * K + kk * 32 + lk4 * 8);
        f32x4 acc = {0.f, 0.f, 0.f, 0.f};
#pragma unroll
        for (int kk = 0; kk < K / 32; kk++)
            acc = __builtin_amdgcn_mfma_f32_16x16x32_bf16(afr[kk], bfr[kk], acc, 0, 0, 0);
        if (T < 64) {
            int h = T & 15, hw = h >> 1, hb = h & 1;
            int ob = ((T >> 4) << 4) + lrow;          // this lane's o
#pragma unroll
            for (int r = 0; r < 4; r++)
                U2[(lk4 * 4 + r) * (2 * ROWW) + hw * 128 + ob * 2 + hb] = f2b(acc[r]);
        } else {
            int col = (T - 64) * 16 + lrow;
#pragma unroll
            for (int r = 0; r < 4; r++)
                XB_l[lk4 * 4 + r][col] = acc[r];
        }
    }
    __syncthreads();

    // ---- edge loop over this block's src-bucket (8 waves interleave)
    const float* Ap = (CONV == 0) ? p.A0p : p.A1p;
    float* aggOut = (CONV == 1) ? p.AGGb : p.AGGa;
    const int beg = p.bucketPtr[b], end = p.bucketPtr[b + 1];
    const int o = l;
#pragma unroll 2
    for (int q0 = beg + w; q0 < end; q0 += 8) {
        int q = __builtin_amdgcn_readfirstlane(q0);
        int mt = p.metap[q];
        int sloc = mt & 15, dd = mt >> 4;
        const float* Ae = Ap + (size_t)q * HID;       // wave-uniform, contiguous
        float av[HID];
#pragma unroll
        for (int h = 0; h < HID; h++) av[h] = Ae[h];
        const unsigned* up = reinterpret_cast<const unsigned*>(U2) + sloc * ROWW + o;
        float m = XB_l[sloc][o];
#define ACC2(wrd, h)                                                              \
        m = fmaf(__builtin_bit_cast(float, (unsigned)(wrd) << 16), av[h], m);     \
        m = fmaf(__builtin_bit_cast(float, (unsigned)(wrd) & 0xffff0000u), av[h + 1], m);
#pragma unroll
        for (int hh = 0; hh < 8; hh++) {
            unsigned uw = up[hh * 64];                // conflict-free ds_read_b32
            ACC2(uw, 2 * hh)
        }
#undef ACC2
        atomicAdd(&aggOut[(size_t)dd * EMB + o], m);
    }
}

// --- conv2 node update + global max pool
__global__ void __launch_bounds__(256) k_upd2(P p) {
    int w = threadIdx.x >> 6, o = threadIdx.x & 63;
    int n = __builtin_amdgcn_readfirstlane(blockIdx.x * 4 + w);
    float s = p.AGGa[n * EMB + o] + p.bias2[o];
    const float* xr = p.X1 + (size_t)n * EMB;    // wave-uniform row -> s_loads
#pragma unroll
    for (int i = 0; i < EMB; i++) s += xr[i] * p.root2[i * EMB + o];
    s = fmaxf(s, 0.f);
    atomicMax((unsigned*)&p.POOL[p.batch[n] * EMB + o], __float_as_uint(s));
}

// --- head: block g, lane o2 computes h[g,o2]; shuffle-reduce h·lin1_w
__global__ void k_head(P p) {
    int g = blockIdx.x, o2 = threadIdx.x;        // 64 blocks x 64 threads
    float h = p.lin0_b[o2];
    const float* Pg = p.POOL + g * EMB;
    for (int o = 0; o < EMB; o++) h += Pg[o] * p.lin0_w[o * EMB + o2];
    float v = h * p.lin1_w[o2];
#pragma unroll
    for (int off = 32; off; off >>= 1) v += __shfl_down(v, off, 64);
    if (o2 == 0) p.out[g] = v + p.lin1_b[0];
}

extern "C" void kernel_launch(void* const* d_in, const int* in_sizes, int n_in,
                              void* d_out, int out_size, void* d_ws, size_t ws_size,
                              hipStream_t stream) {
    P p;
    p.x_p    = (const float*)d_in[0];
    p.ea     = (const float*)d_in[2];
    const int* eidx = (const int*)d_in[4];
    p.src    = eidx;                   // edge_index_p[0]
    p.dst    = eidx + N_EDGES;         // edge_index_p[1]
    p.batch  = (const int*)d_in[5];
    p.nn0_w1 = (const float*)d_in[6];  p.nn0_b1 = (const float*)d_in[7];
    p.nn0_w2 = (const float*)d_in[8];  p.nn0_b2 = (const float*)d_in[9];
    p.nn1_w1 = (const float*)d_in[10]; p.nn1_b1 = (const float*)d_in[11];
    p.nn1_w2 = (const float*)d_in[12]; p.nn1_b2 = (const float*)d_in[13];
    p.root0  = (const float*)d_in[14]; p.bias0  = (const float*)d_in[15];
    p.root1  = (const float*)d_in[16]; p.bias1  = (const float*)d_in[17];
    p.root2  = (const float*)d_in[18]; p.bias2  = (const float*)d_in[19];
    p.lin0_w = (const float*)d_in[20]; p.lin0_b = (const float*)d_in[21];
    p.lin1_w = (const float*)d_in[22]; p.lin1_b = (const float*)d_in[23];
    p.out    = (float*)d_out;

    // workspace (~22 MB). Zero-region first -> one small memset:
    //   bucketCnt (4 KB pad) | AGGa | AGGb | POOL
    char* ws = (char*)d_ws;
    p.bucketCnt = (int*)ws;
    p.AGGa  = (float*)(ws + 4096);
    p.AGGb  = p.AGGa + (size_t)N_NODES * EMB;
    p.POOL  = p.AGGb + (size_t)N_NODES * EMB;
    const size_t ZBYTES = 4096 + ((size_t)2 * N_NODES * EMB + NGRAPH * EMB) * 4;
    char* w2 = ws + ZBYTES;
    p.A0   = (float*)w2;           w2 += (size_t)N_EDGES * HID * 4;
    p.A1   = (float*)w2;           w2 += (size_t)N_EDGES * HID * 4;
    p.A0p  = (float*)w2;           w2 += (size_t)N_EDGES * HID * 4;
    p.A1p  = (float*)w2;           w2 += (size_t)N_EDGES * HID * 4;
    p.W2p0 = (unsigned short*)w2;  w2 += (size_t)NCOL * F_NODE * 2;
    p.W2p1 = (unsigned short*)w2;  w2 += (size_t)NCOL * EMB * 2;
    p.bucketPtr = (int*)w2;        w2 += 2560;   // 626 ints, padded
    p.cursor    = (int*)w2;        w2 += 2560;   // 625 ints, padded
    p.metap     = (int*)w2;        w2 += (size_t)N_EDGES * 4;
    p.X0   = (float*)w2;           w2 += (size_t)N_NODES * EMB * 4;
    p.X1   = (float*)w2;           w2 += (size_t)N_NODES * EMB * 4;

    hipMemsetAsync(p.bucketCnt, 0, ZBYTES, stream);
    k_prep<<<526, 256, 0, stream>>>(p);
    k_scan<<<1, 1024, 0, stream>>>(p);
    k_scatter<<<118, 256, 0, stream>>>(p);
    k_fused<0><<<NBUCK, 512, 0, stream>>>(p);
    k_fused<1><<<NBUCK, 512, 0, stream>>>(p);
    k_fused<2><<<NBUCK, 512, 0, stream>>>(p);
    k_upd2<<<2500, 256, 0, stream>>>(p);
    k_head<<<NGRAPH, 64, 0, stream>>>(p);
}

// Round 8
// 211.813 us; speedup vs baseline: 7.5463x; 1.1158x over previous
//
#include <hip/hip_runtime.h>
#include <hip/hip_bf16.h>

#define N_NODES 10000
#define N_EDGES 30000
#define F_NODE  32
#define F_EDGE  8
#define EMB     64
#define HID     16
#define NGRAPH  64
#define NBUCK   625              // 10000/16 exact
#define CAP     128              // slots per src-bucket (mean 48, P(>=128)~1e-20)
#define NCOL    1088             // 1024 U cols + 64 XB cols
#define ROWW    514              // U_lds row stride in words (514%32=2 -> bank spread)

typedef __attribute__((ext_vector_type(8))) short short8;   // 8 bf16 (MFMA A/B frag)
typedef __attribute__((ext_vector_type(4))) float f32x4;    // MFMA C/D frag

__device__ __forceinline__ unsigned short f2b(float f) {
    __hip_bfloat16 h = __float2bfloat16(f);
    return __builtin_bit_cast(unsigned short, h);
}

struct P {
    const float *x_p, *ea;
    const int *src, *dst, *batch;
    const float *nn0_w1, *nn0_b1, *nn0_w2, *nn0_b2;
    const float *nn1_w1, *nn1_b1, *nn1_w2, *nn1_b2;
    const float *root0, *bias0, *root1, *bias1, *root2, *bias2;
    const float *lin0_w, *lin0_b, *lin1_w, *lin1_b;
    float *out;
    int *cursor, *metap;
    float *A0p, *A1p;
    unsigned short *W2p0, *W2p1;
    float *AGGa, *AGGb, *X0, *X1, *POOL;
};

// ---------------------------------------------------------------------------
// prep (heterogeneous blocks):
//   [0,118)    edge blocks: edge-MLP hiddens in REGISTERS -> written directly
//              into fixed-capacity src-buckets (pos = atomicAdd(cursor)),
//              plus meta = dst*16+sloc. No scan, no second pass.
//   [118,254)  W2p0 permute (K=32), transposed tile order (R7 conflict fix):
//              tile T<64 holds {o=(T>>4)*16+lr, h=T&15}; T>=64 are b2 cols.
//   [254,526)  W2p1 permute (K=64), same order.
//   [526,686)  zero AGGa|POOL (contiguous region, float4).
// ---------------------------------------------------------------------------
__global__ void __launch_bounds__(256) k_prep(P p) {
    int b = blockIdx.x, t = threadIdx.x;
    if (b < 118) {
        int e = b * 256 + t;
        if (e >= N_EDGES) return;
        float f[F_EDGE];
#pragma unroll
        for (int i = 0; i < F_EDGE; i++) f[i] = p.ea[e * F_EDGE + i];
        float a0[HID], a1[HID];
#pragma unroll
        for (int h = 0; h < HID; h++) {
            float s0 = p.nn0_b1[h], s1 = p.nn1_b1[h];
#pragma unroll
            for (int i = 0; i < F_EDGE; i++) {
                s0 += f[i] * p.nn0_w1[i * HID + h];
                s1 += f[i] * p.nn1_w1[i * HID + h];
            }
            a0[h] = fmaxf(s0, 0.f);
            a1[h] = fmaxf(s1, 0.f);
        }
        int s = p.src[e];
        int bk = s >> 4;
        int pos = atomicAdd(&p.cursor[bk], 1);
        if (pos < CAP) {
            size_t base = (size_t)bk * CAP + pos;
            p.metap[base] = p.dst[e] * 16 + (s & 15);
#pragma unroll
            for (int h = 0; h < HID; h++) {
                p.A0p[base * HID + h] = a0[h];
                p.A1p[base * HID + h] = a1[h];
            }
        }
    } else if (b < 254) {                       // W2p0 (K=32): 34816 elems
        int i = (b - 118) * 256 + t;
        if (i >= NCOL * F_NODE) return;
        int rt = i >> 5, k = i & 31;
        float v;
        if (rt < 1024) {
            int T = rt >> 4, lr = rt & 15;
            int o = ((T >> 4) << 4) + lr, h = T & 15;
            v = p.nn0_w2[h * (F_NODE * EMB) + k * EMB + o];
        } else {
            v = p.nn0_b2[k * EMB + (rt - 1024)];
        }
        p.W2p0[i] = f2b(v);
    } else if (b < 526) {                       // W2p1 (K=64): 69632 elems
        int i = (b - 254) * 256 + t;
        if (i >= NCOL * EMB) return;
        int rt = i >> 6, k = i & 63;
        float v;
        if (rt < 1024) {
            int T = rt >> 4, lr = rt & 15;
            int o = ((T >> 4) << 4) + lr, h = T & 15;
            v = p.nn1_w2[h * (EMB * EMB) + k * EMB + o];
        } else {
            v = p.nn1_b2[k * EMB + (rt - 1024)];
        }
        p.W2p1[i] = f2b(v);
    } else {                                    // zero AGGa|POOL: 161024 float4
        int idx = (b - 526) * 256 + t;
        float4* Z = (float4*)p.AGGa;            // POOL is contiguous after AGGa
        const float4 z4 = {0.f, 0.f, 0.f, 0.f};
        for (int i = idx; i < (N_NODES * EMB + NGRAPH * EMB) / 4; i += 160 * 256)
            Z[i] = z4;
    }
}

// ---------------------------------------------------------------------------
// Fused conv kernel, 512 threads (8 waves), block b owns nodes [16b,16b+16):
//   CONV==0: zero own AGGb rows (ready for conv1 at the kernel boundary).
//   CONV>0 prologue: X_{c-1} rows from AGG+root+bias; conv1 re-zeros AGGa.
//   MFMA: U tile -> LDS only; word = row*514 + (h>>1)*64 + o (subword h&1);
//         writes conflict-free (transposed W2p tiles), reads conflict-free.
//   Edge loop: bucket slots (contiguous meta + A s_loads, unroll 2);
//              msg -> atomicAdd AGG_out[dst].
// AGG ping-pong: conv0->AGGa, conv1->AGGb (zeroes AGGa), conv2->AGGa.
// ---------------------------------------------------------------------------
template <int CONV>
__global__ void __launch_bounds__(512) k_fused(P p) {
    constexpr int K = (CONV == 0) ? F_NODE : EMB;
    __shared__ unsigned short U2[16 * 2 * ROWW];   // 16 rows x 514 words = 32.9 KB
    __shared__ float XB_l[16][65];
    __shared__ float Xt[16][65];
    const int b = blockIdx.x, t = threadIdx.x;
    const int n0 = b * 16;
    const int w = t >> 6, l = t & 63;
    const int lrow = l & 15, lk4 = l >> 4;

    if (CONV == 0) {     // zero own AGGb rows for conv1
        float4* Zb = (float4*)(p.AGGb + (size_t)n0 * EMB);
        const float4 z4 = {0.f, 0.f, 0.f, 0.f};
        for (int idx = t; idx < 16 * EMB / 4; idx += 512) Zb[idx] = z4;
    }

    if (CONV > 0) {      // prologue: previous conv's node update for own rows
        const float* aggIn = (CONV == 1) ? p.AGGa : p.AGGb;
        const float* rt = (CONV == 1) ? p.root0 : p.root1;
        const float* bs = (CONV == 1) ? p.bias0 : p.bias1;
        constexpr int IN = (CONV == 1) ? F_NODE : EMB;
        for (int idx = t; idx < 16 * 64; idx += 512) {
            int j = idx >> 6, o = idx & 63;
            int n = n0 + j;
            float s = aggIn[n * EMB + o] + bs[o];
            const float* xr = (CONV == 1) ? (p.x_p + (size_t)n * IN)
                                          : (p.X0 + (size_t)n * IN);
#pragma unroll
            for (int i = 0; i < IN; i++) s += xr[i] * rt[i * EMB + o];
            float sv = fmaxf(s, 0.f);
            Xt[j][o] = sv;
            if (CONV == 1) { p.X0[n * EMB + o] = sv; p.AGGa[n * EMB + o] = 0.f; }
            else           { p.X1[n * EMB + o] = sv; }
        }
        __syncthreads();
    }

    // ---- MFMA: C[16 x 1088] = X_tile @ W2p^T  (tiles T = w + 8i)
    short8 afr[K / 32];
    if (CONV == 0) {
        const float* xp = p.x_p + (size_t)(n0 + lrow) * F_NODE + lk4 * 8;
#pragma unroll
        for (int q = 0; q < 8; q++) afr[0][q] = (short)f2b(xp[q]);
    } else {
#pragma unroll
        for (int kk = 0; kk < K / 32; kk++)
#pragma unroll
            for (int q = 0; q < 8; q++)
                afr[kk][q] = (short)f2b(Xt[lrow][kk * 32 + lk4 * 8 + q]);
    }
    const unsigned short* W2p = (CONV == 0) ? p.W2p0 : p.W2p1;
    for (int i = 0; i <= 8; i++) {
        int T = w + 8 * i;
        if (T >= 68) break;
        short8 bfr[K / 32];
#pragma unroll
        for (int kk = 0; kk < K / 32; kk++)
            bfr[kk] = *reinterpret_cast<const short8*>(
                W2p + (size_t)(T * 16 + lrow) * K + kk * 32 + lk4 * 8);
        f32x4 acc = {0.f, 0.f, 0.f, 0.f};
#pragma unroll
        for (int kk = 0; kk < K / 32; kk++)
            acc = __builtin_amdgcn_mfma_f32_16x16x32_bf16(afr[kk], bfr[kk], acc, 0, 0, 0);
        if (T < 64) {
            int h = T & 15, hw = h >> 1, hb = h & 1;
            int ob = ((T >> 4) << 4) + lrow;          // this lane's o
#pragma unroll
            for (int r = 0; r < 4; r++)
                U2[(lk4 * 4 + r) * (2 * ROWW) + hw * 128 + ob * 2 + hb] = f2b(acc[r]);
        } else {
            int col = (T - 64) * 16 + lrow;
#pragma unroll
            for (int r = 0; r < 4; r++)
                XB_l[lk4 * 4 + r][col] = acc[r];
        }
    }
    __syncthreads();

    // ---- edge loop over this block's src-bucket slots (8 waves interleave)
    const float* Ap = (CONV == 0) ? p.A0p : p.A1p;
    float* aggOut = (CONV == 1) ? p.AGGb : p.AGGa;
    int cnt = p.cursor[b];
    if (cnt > CAP) cnt = CAP;
    const size_t base = (size_t)b * CAP;
    const int o = l;
#pragma unroll 2
    for (int qi = w; qi < cnt; qi += 8) {
        int q = __builtin_amdgcn_readfirstlane(qi);
        int mt = p.metap[base + q];
        int sloc = mt & 15, dd = mt >> 4;
        const float* Ae = Ap + (base + q) * HID;      // wave-uniform, contiguous
        float av[HID];
#pragma unroll
        for (int h = 0; h < HID; h++) av[h] = Ae[h];
        const unsigned* up = reinterpret_cast<const unsigned*>(U2) + sloc * ROWW + o;
        float m = XB_l[sloc][o];
#define ACC2(wrd, h)                                                              \
        m = fmaf(__builtin_bit_cast(float, (unsigned)(wrd) << 16), av[h], m);     \
        m = fmaf(__builtin_bit_cast(float, (unsigned)(wrd) & 0xffff0000u), av[h + 1], m);
#pragma unroll
        for (int hh = 0; hh < 8; hh++) {
            unsigned uw = up[hh * 64];                // conflict-free ds_read_b32
            ACC2(uw, 2 * hh)
        }
#undef ACC2
        atomicAdd(&aggOut[(size_t)dd * EMB + o], m);
    }
}

// --- conv2 node update + global max pool
__global__ void __launch_bounds__(256) k_upd2(P p) {
    int w = threadIdx.x >> 6, o = threadIdx.x & 63;
    int n = __builtin_amdgcn_readfirstlane(blockIdx.x * 4 + w);
    float s = p.AGGa[n * EMB + o] + p.bias2[o];
    const float* xr = p.X1 + (size_t)n * EMB;    // wave-uniform row -> s_loads
#pragma unroll
    for (int i = 0; i < EMB; i++) s += xr[i] * p.root2[i * EMB + o];
    s = fmaxf(s, 0.f);
    atomicMax((unsigned*)&p.POOL[p.batch[n] * EMB + o], __float_as_uint(s));
}

// --- head: block g, lane o2 computes h[g,o2]; shuffle-reduce h·lin1_w
__global__ void k_head(P p) {
    int g = blockIdx.x, o2 = threadIdx.x;        // 64 blocks x 64 threads
    float h = p.lin0_b[o2];
    const float* Pg = p.POOL + g * EMB;
    for (int o = 0; o < EMB; o++) h += Pg[o] * p.lin0_w[o * EMB + o2];
    float v = h * p.lin1_w[o2];
#pragma unroll
    for (int off = 32; off; off >>= 1) v += __shfl_down(v, off, 64);
    if (o2 == 0) p.out[g] = v + p.lin1_b[0];
}

extern "C" void kernel_launch(void* const* d_in, const int* in_sizes, int n_in,
                              void* d_out, int out_size, void* d_ws, size_t ws_size,
                              hipStream_t stream) {
    P p;
    p.x_p    = (const float*)d_in[0];
    p.ea     = (const float*)d_in[2];
    const int* eidx = (const int*)d_in[4];
    p.src    = eidx;                   // edge_index_p[0]
    p.dst    = eidx + N_EDGES;         // edge_index_p[1]
    p.batch  = (const int*)d_in[5];
    p.nn0_w1 = (const float*)d_in[6];  p.nn0_b1 = (const float*)d_in[7];
    p.nn0_w2 = (const float*)d_in[8];  p.nn0_b2 = (const float*)d_in[9];
    p.nn1_w1 = (const float*)d_in[10]; p.nn1_b1 = (const float*)d_in[11];
    p.nn1_w2 = (const float*)d_in[12]; p.nn1_b2 = (const float*)d_in[13];
    p.root0  = (const float*)d_in[14]; p.bias0  = (const float*)d_in[15];
    p.root1  = (const float*)d_in[16]; p.bias1  = (const float*)d_in[17];
    p.root2  = (const float*)d_in[18]; p.bias2  = (const float*)d_in[19];
    p.lin0_w = (const float*)d_in[20]; p.lin0_b = (const float*)d_in[21];
    p.lin1_w = (const float*)d_in[22]; p.lin1_b = (const float*)d_in[23];
    p.out    = (float*)d_out;

    // workspace (~24 MB):
    //   cursor (4 KB, memset) | AGGa | POOL (contig zero-region) | AGGb | ...
    char* ws = (char*)d_ws;
    p.cursor = (int*)ws;
    p.AGGa  = (float*)(ws + 4096);
    p.POOL  = p.AGGa + (size_t)N_NODES * EMB;        // contiguous after AGGa
    p.AGGb  = p.POOL + (size_t)NGRAPH * EMB;
    char* w2 = (char*)(p.AGGb + (size_t)N_NODES * EMB);
    p.metap = (int*)w2;            w2 += (size_t)NBUCK * CAP * 4;
    p.A0p   = (float*)w2;          w2 += (size_t)NBUCK * CAP * HID * 4;
    p.A1p   = (float*)w2;          w2 += (size_t)NBUCK * CAP * HID * 4;
    p.W2p0  = (unsigned short*)w2; w2 += (size_t)NCOL * F_NODE * 2;
    p.W2p1  = (unsigned short*)w2; w2 += (size_t)NCOL * EMB * 2;
    p.X0    = (float*)w2;          w2 += (size_t)N_NODES * EMB * 4;
    p.X1    = (float*)w2;          w2 += (size_t)N_NODES * EMB * 4;

    hipMemsetAsync(p.cursor, 0, 4096, stream);
    k_prep<<<686, 256, 0, stream>>>(p);
    k_fused<0><<<NBUCK, 512, 0, stream>>>(p);
    k_fused<1><<<NBUCK, 512, 0, stream>>>(p);
    k_fused<2><<<NBUCK, 512, 0, stream>>>(p);
    k_upd2<<<2500, 256, 0, stream>>>(p);
    k_head<<<NGRAPH, 64, 0, stream>>>(p);
}

// Round 10
// 203.336 us; speedup vs baseline: 7.8609x; 1.0417x over previous
//
#include <hip/hip_runtime.h>
#include <hip/hip_bf16.h>

#define N_NODES 10000
#define N_EDGES 30000
#define F_NODE  32
#define F_EDGE  8
#define EMB     64
#define HID     16
#define NGRAPH  64
#define NBUCK   625              // 10000/16 exact
#define CAP     128              // slots per src-bucket (mean 48, P(>=128)~1e-20; held r6-r8)
#define NCOL    1088             // 1024 U cols + 64 XB cols
#define ROWW    514              // U_lds row stride in words (514%32=2 -> bank spread)

typedef __attribute__((ext_vector_type(8))) short short8;   // 8 bf16 (MFMA A/B frag)
typedef __attribute__((ext_vector_type(4))) float f32x4;    // MFMA C/D frag

__device__ __forceinline__ unsigned short f2b(float f) {
    __hip_bfloat16 h = __float2bfloat16(f);
    return __builtin_bit_cast(unsigned short, h);
}

struct P {
    const float *x_p, *ea;
    const int *src, *dst, *batch;
    const float *nn0_w1, *nn0_b1, *nn0_w2, *nn0_b2;
    const float *nn1_w1, *nn1_b1, *nn1_w2, *nn1_b2;
    const float *root0, *bias0, *root1, *bias1, *root2, *bias2;
    const float *lin0_w, *lin0_b, *lin1_w, *lin1_b;
    float *out;
    int *cnt, *metap;
    float *A1p;
    unsigned short *W2p0, *W2p1;
    float *AGGa, *AGGb, *X0, *X1, *POOL;
};

// ---------------------------------------------------------------------------
// prep: W2p permutes + zeroing only (edge work lives in k_fused<0>).
//   [0,136)    W2p0 (K=32), transposed tile order (r7 conflict fix):
//              tile T<64 holds {o=(T>>4)*16+lr, h=T&15}; T>=64 are b2 cols.
//   [136,408)  W2p1 (K=64), same order.
//   [408,568)  zero AGGa|POOL (contiguous region, float4).
// No cursor, no memset, no cross-block anything.
// ---------------------------------------------------------------------------
__global__ void __launch_bounds__(256) k_prep(P p) {
    int b = blockIdx.x, t = threadIdx.x;
    if (b < 136) {                              // W2p0 (K=32): 34816 elems
        int i = b * 256 + t;
        if (i >= NCOL * F_NODE) return;
        int rt = i >> 5, k = i & 31;
        float v;
        if (rt < 1024) {
            int T = rt >> 4, lr = rt & 15;
            int o = ((T >> 4) << 4) + lr, h = T & 15;
            v = p.nn0_w2[h * (F_NODE * EMB) + k * EMB + o];
        } else {
            v = p.nn0_b2[k * EMB + (rt - 1024)];
        }
        p.W2p0[i] = f2b(v);
    } else if (b < 408) {                       // W2p1 (K=64): 69632 elems
        int i = (b - 136) * 256 + t;
        if (i >= NCOL * EMB) return;
        int rt = i >> 6, k = i & 63;
        float v;
        if (rt < 1024) {
            int T = rt >> 4, lr = rt & 15;
            int o = ((T >> 4) << 4) + lr, h = T & 15;
            v = p.nn1_w2[h * (EMB * EMB) + k * EMB + o];
        } else {
            v = p.nn1_b2[k * EMB + (rt - 1024)];
        }
        p.W2p1[i] = f2b(v);
    } else {                                    // zero AGGa|POOL
        int idx = (b - 408) * 256 + t;
        float4* Z = (float4*)p.AGGa;            // POOL contiguous after AGGa
        const float4 z4 = {0.f, 0.f, 0.f, 0.f};
        const int nv4 = (N_NODES * EMB + NGRAPH * EMB) / 4;
        for (int i = idx; i < nv4; i += 160 * 256) Z[i] = z4;
    }
}

// ---------------------------------------------------------------------------
// Fused conv kernel, 512 threads (8 waves), block b owns nodes [16b,16b+16):
//   CONV==0: zero own AGGb rows; build own src-bucket by SCANNING src
//     (15 int4 loads/thread, LDS-atomic append only — no global cursor);
//     phase B: edge-MLP for own edges (a0 -> LDS, consumed here;
//     a1+meta+cnt -> block-owned global slots for f1/f2).
//   CONV>0 prologue: X_{c-1} rows from AGG+root+bias; conv1 re-zeros AGGa.
//   MFMA: U tile -> LDS only; word = row*514 + (h>>1)*64 + o (subword h&1);
//         conflict-free writes (transposed W2p tiles) and reads (r7-verified,
//         SQ_LDS_BANK_CONFLICT 4.9M -> 0).
//   Edge loop: msg = XB + sum_h A*U -> atomicAdd AGG_out[dst].
// AGG ping-pong: conv0->AGGa, conv1->AGGb (zeroes AGGa), conv2->AGGa.
// All work is per-block bounded; only cross-block ops are plain atomics.
// ---------------------------------------------------------------------------
template <int CONV>
__global__ void __launch_bounds__(512) k_fused(P p) {
    constexpr int K = (CONV == 0) ? F_NODE : EMB;
    __shared__ unsigned short U2[16 * 2 * ROWW];   // 32.9 KB
    __shared__ float XB_l[16][65];
    __shared__ float Xt[16][65];
    __shared__ float A0l[CAP][HID];                // 8 KB (f0 only; DCE'd in f1/f2)
    __shared__ int lds_e[CAP];
    __shared__ int meta_l[CAP];
    __shared__ int lcnt;
    const int b = blockIdx.x, t = threadIdx.x;
    const int n0 = b * 16;
    const int w = t >> 6, l = t & 63;
    const int lrow = l & 15, lk4 = l >> 4;
    int cnt = 0;

    if (CONV == 0) {
        // zero own AGGb rows (ready for conv1 at the boundary)
        float4* Zb = (float4*)(p.AGGb + (size_t)n0 * EMB);
        const float4 z4 = {0.f, 0.f, 0.f, 0.f};
        for (int idx = t; idx < 16 * EMB / 4; idx += 512) Zb[idx] = z4;
        // phase A: scan src (30000 ints, L1/L2-resident), collect own edges
        if (t == 0) lcnt = 0;
        __syncthreads();
        const int4* s4 = (const int4*)p.src;
        for (int i = t; i < N_EDGES / 4; i += 512) {
            int4 v = s4[i];
            int e0 = i * 4;
            if ((v.x >> 4) == b) { int sl = atomicAdd(&lcnt, 1); if (sl < CAP) lds_e[sl] = ((e0    ) << 4) | (v.x & 15); }
            if ((v.y >> 4) == b) { int sl = atomicAdd(&lcnt, 1); if (sl < CAP) lds_e[sl] = ((e0 + 1) << 4) | (v.y & 15); }
            if ((v.z >> 4) == b) { int sl = atomicAdd(&lcnt, 1); if (sl < CAP) lds_e[sl] = ((e0 + 2) << 4) | (v.z & 15); }
            if ((v.w >> 4) == b) { int sl = atomicAdd(&lcnt, 1); if (sl < CAP) lds_e[sl] = ((e0 + 3) << 4) | (v.w & 15); }
        }
        __syncthreads();
        cnt = lcnt; if (cnt > CAP) cnt = CAP;
        if (t == 0) p.cnt[b] = cnt;
        // phase B: edge-MLP for own edges (first cnt threads; ~48 typical)
        if (t < cnt) {
            int pk = lds_e[t];
            int e = pk >> 4, sloc = pk & 15;
            int mt = p.dst[e] * 16 + sloc;
            meta_l[t] = mt;
            p.metap[(size_t)b * CAP + t] = mt;
            const float4* ea4 = (const float4*)(p.ea + (size_t)e * F_EDGE);
            float4 ef0 = ea4[0], ef1 = ea4[1];
            float fv[F_EDGE] = {ef0.x, ef0.y, ef0.z, ef0.w, ef1.x, ef1.y, ef1.z, ef1.w};
            float a1v[HID];
#pragma unroll
            for (int h = 0; h < HID; h++) {
                float s0 = p.nn0_b1[h], s1 = p.nn1_b1[h];
#pragma unroll
                for (int i = 0; i < F_EDGE; i++) {
                    s0 += fv[i] * p.nn0_w1[i * HID + h];
                    s1 += fv[i] * p.nn1_w1[i * HID + h];
                }
                A0l[t][h] = fmaxf(s0, 0.f);
                a1v[h] = fmaxf(s1, 0.f);
            }
            float4* A1g = (float4*)(p.A1p + ((size_t)b * CAP + t) * HID);
#pragma unroll
            for (int j = 0; j < 4; j++)
                A1g[j] = float4{a1v[4 * j], a1v[4 * j + 1], a1v[4 * j + 2], a1v[4 * j + 3]};
        }
        // A0l/meta_l visibility covered by the post-MFMA __syncthreads
    }

    if (CONV > 0) {      // prologue: previous conv's node update for own rows
        const float* aggIn = (CONV == 1) ? p.AGGa : p.AGGb;
        const float* rt = (CONV == 1) ? p.root0 : p.root1;
        const float* bs = (CONV == 1) ? p.bias0 : p.bias1;
        constexpr int IN = (CONV == 1) ? F_NODE : EMB;
        for (int idx = t; idx < 16 * 64; idx += 512) {
            int j = idx >> 6, o = idx & 63;
            int n = n0 + j;
            float s = aggIn[n * EMB + o] + bs[o];
            const float* xr = (CONV == 1) ? (p.x_p + (size_t)n * IN)
                                          : (p.X0 + (size_t)n * IN);
#pragma unroll
            for (int i = 0; i < IN; i++) s += xr[i] * rt[i * EMB + o];
            float sv = fmaxf(s, 0.f);
            Xt[j][o] = sv;
            if (CONV == 1) { p.X0[n * EMB + o] = sv; p.AGGa[n * EMB + o] = 0.f; }
            else           { p.X1[n * EMB + o] = sv; }
        }
        __syncthreads();
        cnt = p.cnt[b];
    }

    // ---- MFMA: C[16 x 1088] = X_tile @ W2p^T  (tiles T = w + 8i)
    short8 afr[K / 32];
    if (CONV == 0) {
        const float* xp = p.x_p + (size_t)(n0 + lrow) * F_NODE + lk4 * 8;
#pragma unroll
        for (int q = 0; q < 8; q++) afr[0][q] = (short)f2b(xp[q]);
    } else {
#pragma unroll
        for (int kk = 0; kk < K / 32; kk++)
#pragma unroll
            for (int q = 0; q < 8; q++)
                afr[kk][q] = (short)f2b(Xt[lrow][kk * 32 + lk4 * 8 + q]);
    }
    const unsigned short* W2p = (CONV == 0) ? p.W2p0 : p.W2p1;
    for (int i = 0; i <= 8; i++) {
        int T = w + 8 * i;
        if (T >= 68) break;
        short8 bfr[K / 32];
#pragma unroll
        for (int kk = 0; kk < K / 32; kk++)
            bfr[kk] = *reinterpret_cast<const short8*>(
                W2p + (size_t)(T * 16 + lrow) * K + kk * 32 + lk4 * 8);
        f32x4 acc = {0.f, 0.f, 0.f, 0.f};
#pragma unroll
        for (int kk = 0; kk < K / 32; kk++)
            acc = __builtin_amdgcn_mfma_f32_16x16x32_bf16(afr[kk], bfr[kk], acc, 0, 0, 0);
        if (T < 64) {
            int h = T & 15, hw = h >> 1, hb = h & 1;
            int ob = ((T >> 4) << 4) + lrow;          // this lane's o
#pragma unroll
            for (int r = 0; r < 4; r++)
                U2[(lk4 * 4 + r) * (2 * ROWW) + hw * 128 + ob * 2 + hb] = f2b(acc[r]);
        } else {
            int col = (T - 64) * 16 + lrow;
#pragma unroll
            for (int r = 0; r < 4; r++)
                XB_l[lk4 * 4 + r][col] = acc[r];
        }
    }
    __syncthreads();

    // ---- edge loop over this block's bucket (8 waves interleave)
    float* aggOut = (CONV == 1) ? p.AGGb : p.AGGa;
    const size_t base = (size_t)b * CAP;
    const int o = l;
#pragma unroll 2
    for (int qi = w; qi < cnt; qi += 8) {
        int q = __builtin_amdgcn_readfirstlane(qi);
        int mt;
        float av[HID];
        if (CONV == 0) {
            mt = meta_l[q];
            const float4* a4 = (const float4*)A0l[q];     // LDS broadcast b128
            float4 u0 = a4[0], u1 = a4[1], u2 = a4[2], u3 = a4[3];
            av[0]=u0.x; av[1]=u0.y; av[2]=u0.z; av[3]=u0.w;
            av[4]=u1.x; av[5]=u1.y; av[6]=u1.z; av[7]=u1.w;
            av[8]=u2.x; av[9]=u2.y; av[10]=u2.z; av[11]=u2.w;
            av[12]=u3.x; av[13]=u3.y; av[14]=u3.z; av[15]=u3.w;
        } else {
            mt = p.metap[base + q];                       // s_load (q uniform)
            const float* Ae = p.A1p + (base + q) * HID;   // contiguous s_loads
#pragma unroll
            for (int h = 0; h < HID; h++) av[h] = Ae[h];
        }
        int sloc = mt & 15, dd = mt >> 4;
        const unsigned* up = reinterpret_cast<const unsigned*>(U2) + sloc * ROWW + o;
        float m = XB_l[sloc][o];
#define ACC2(wrd, h)                                                              \
        m = fmaf(__builtin_bit_cast(float, (unsigned)(wrd) << 16), av[h], m);     \
        m = fmaf(__builtin_bit_cast(float, (unsigned)(wrd) & 0xffff0000u), av[h + 1], m);
#pragma unroll
        for (int hh = 0; hh < 8; hh++) {
            unsigned uw = up[hh * 64];                    // conflict-free ds_read
            ACC2(uw, 2 * hh)
        }
#undef ACC2
        atomicAdd(&aggOut[(size_t)dd * EMB + o], m);
    }
}

// --- conv2 node update + global max pool (plain; no cross-block tricks)
__global__ void __launch_bounds__(256) k_upd2(P p) {
    int w = threadIdx.x >> 6, o = threadIdx.x & 63;
    int n = __builtin_amdgcn_readfirstlane(blockIdx.x * 4 + w);
    float s = p.AGGa[n * EMB + o] + p.bias2[o];
    const float* xr = p.X1 + (size_t)n * EMB;    // wave-uniform row -> s_loads
#pragma unroll
    for (int i = 0; i < EMB; i++) s += xr[i] * p.root2[i * EMB + o];
    s = fmaxf(s, 0.f);
    atomicMax((unsigned*)&p.POOL[p.batch[n] * EMB + o], __float_as_uint(s));
}

// --- head: block g, lane o2 computes h[g,o2]; shuffle-reduce h·lin1_w
__global__ void k_head(P p) {
    int g = blockIdx.x, o2 = threadIdx.x;        // 64 blocks x 64 threads
    float h = p.lin0_b[o2];
    const float* Pg = p.POOL + g * EMB;
    for (int o = 0; o < EMB; o++) h += Pg[o] * p.lin0_w[o * EMB + o2];
    float v = h * p.lin1_w[o2];
#pragma unroll
    for (int off = 32; off; off >>= 1) v += __shfl_down(v, off, 64);
    if (o2 == 0) p.out[g] = v + p.lin1_b[0];
}

extern "C" void kernel_launch(void* const* d_in, const int* in_sizes, int n_in,
                              void* d_out, int out_size, void* d_ws, size_t ws_size,
                              hipStream_t stream) {
    P p;
    p.x_p    = (const float*)d_in[0];
    p.ea     = (const float*)d_in[2];
    const int* eidx = (const int*)d_in[4];
    p.src    = eidx;                   // edge_index_p[0]
    p.dst    = eidx + N_EDGES;         // edge_index_p[1]
    p.batch  = (const int*)d_in[5];
    p.nn0_w1 = (const float*)d_in[6];  p.nn0_b1 = (const float*)d_in[7];
    p.nn0_w2 = (const float*)d_in[8];  p.nn0_b2 = (const float*)d_in[9];
    p.nn1_w1 = (const float*)d_in[10]; p.nn1_b1 = (const float*)d_in[11];
    p.nn1_w2 = (const float*)d_in[12]; p.nn1_b2 = (const float*)d_in[13];
    p.root0  = (const float*)d_in[14]; p.bias0  = (const float*)d_in[15];
    p.root1  = (const float*)d_in[16]; p.bias1  = (const float*)d_in[17];
    p.root2  = (const float*)d_in[18]; p.bias2  = (const float*)d_in[19];
    p.lin0_w = (const float*)d_in[20]; p.lin0_b = (const float*)d_in[21];
    p.lin1_w = (const float*)d_in[22]; p.lin1_b = (const float*)d_in[23];
    p.out    = (float*)d_out;

    // workspace (~16 MB). Zero region (done by prep): AGGa | POOL.
    char* ws = (char*)d_ws;
    p.AGGa   = (float*)ws;
    p.POOL   = p.AGGa + (size_t)N_NODES * EMB;       // contiguous after AGGa
    char* w2 = (char*)(p.POOL + (size_t)NGRAPH * EMB);
    p.AGGb   = (float*)w2;          w2 += (size_t)N_NODES * EMB * 4;
    p.cnt    = (int*)w2;            w2 += 2560;      // 625 ints, padded
    p.metap  = (int*)w2;            w2 += (size_t)NBUCK * CAP * 4;
    p.A1p    = (float*)w2;          w2 += (size_t)NBUCK * CAP * HID * 4;
    p.W2p0   = (unsigned short*)w2; w2 += (size_t)NCOL * F_NODE * 2;
    p.W2p1   = (unsigned short*)w2; w2 += (size_t)NCOL * EMB * 2;
    p.X0     = (float*)w2;          w2 += (size_t)N_NODES * EMB * 4;
    p.X1     = (float*)w2;          w2 += (size_t)N_NODES * EMB * 4;

    k_prep<<<568, 256, 0, stream>>>(p);
    k_fused<0><<<NBUCK, 512, 0, stream>>>(p);
    k_fused<1><<<NBUCK, 512, 0, stream>>>(p);
    k_fused<2><<<NBUCK, 512, 0, stream>>>(p);
    k_upd2<<<2500, 256, 0, stream>>>(p);
    k_head<<<NGRAPH, 64, 0, stream>>>(p);
}